// Round 1
// baseline (68263.226 us; speedup 1.0000x reference)
//
#include <hip/hip_runtime.h>
#include <hip/hip_bf16.h>

#define HD 128
#define NGAUSS 50
#define NLAYER 6
#define NGRAPH 16
#define NCLS 97

__device__ __forceinline__ float ssp_f(float x) {
    // softplus(x) - log(2), numerically stable
    return fmaxf(x, 0.0f) + log1pf(__expf(-fabsf(x))) - 0.69314718055994531f;
}

// ---------------- edge geometry: distance + cosine cutoff ----------------
__global__ void geom_kernel(const float* __restrict__ pos,
                            const int* __restrict__ row, const int* __restrict__ col,
                            float* __restrict__ ew, float* __restrict__ cenv, int E) {
    int e = blockIdx.x * blockDim.x + threadIdx.x;
    if (e >= E) return;
    int r = row[e], c = col[e];
    float dx = pos[r*3+0] - pos[c*3+0];
    float dy = pos[r*3+1] - pos[c*3+1];
    float dz = pos[r*3+2] - pos[c*3+2];
    float w = sqrtf(dx*dx + dy*dy + dz*dz);
    ew[e] = w;
    cenv[e] = 0.5f * (cosf(w * 0.31415926535897931f) + 1.0f);  // pi/10
}

// ---------------- embedding: h = x @ emb_w + emb_b ----------------
__global__ void embed_kernel(const float* __restrict__ x,
                             const float* __restrict__ emb_w, const float* __restrict__ emb_b,
                             float* __restrict__ h, int N) {
    int idx = blockIdx.x * blockDim.x + threadIdx.x;
    if (idx >= N * HD) return;
    int n = idx >> 7, t = idx & 127;
    float acc = emb_b[t];
    #pragma unroll
    for (int a = 0; a < 21; ++a) acc += x[n*21 + a] * emb_w[a*HD + t];
    h[idx] = acc;
}

// ---------------- generic 128x128 GEMV over rows ----------------
// out[n][t] = epilogue( sum_k in[n][k] * W[k][t] (+ bias[t]) ) (+ out[n][t] if RES)
// ACT: 0 none, 1 shifted-softplus, 2 relu
template<int ACT, bool BIAS, bool RES>
__global__ __launch_bounds__(256) void gemv128_kernel(
        const float* __restrict__ in, const float* __restrict__ W,
        const float* __restrict__ bias, float* __restrict__ out, int nrows) {
    __shared__ __align__(16) float rows_sm[2][4][HD];
    const int tid = threadIdx.x;
    const int t = tid & 127, grp = tid >> 7;

    float w_r[HD];
    #pragma unroll
    for (int k = 0; k < HD; ++k) w_r[k] = W[k*HD + t];
    const float bt = BIAS ? bias[t] : 0.0f;

    for (int base = blockIdx.x * 8; base < nrows; base += gridDim.x * 8) {
        const int n0 = base + grp * 4;
        __syncthreads();
        #pragma unroll
        for (int e = 0; e < 4; ++e) {
            int n = n0 + e;
            rows_sm[grp][e][t] = (n < nrows) ? in[n*HD + t] : 0.0f;
        }
        __syncthreads();

        float acc[4] = {0.f, 0.f, 0.f, 0.f};
        #pragma unroll
        for (int q = 0; q < 32; ++q) {
            #pragma unroll
            for (int e = 0; e < 4; ++e) {
                float4 v = reinterpret_cast<const float4*>(rows_sm[grp][e])[q];
                acc[e] += v.x * w_r[4*q+0] + v.y * w_r[4*q+1]
                        + v.z * w_r[4*q+2] + v.w * w_r[4*q+3];
            }
        }
        #pragma unroll
        for (int e = 0; e < 4; ++e) {
            int n = n0 + e;
            if (n < nrows) {
                float v = acc[e] + bt;
                if (ACT == 1) v = ssp_f(v);
                if (ACT == 2) v = fmaxf(v, 0.0f);
                if (RES) v += out[n*HD + t];
                out[n*HD + t] = v;
            }
        }
    }
}

// ---------------- fused edge kernel ----------------
// Per edge: ea = exp(coeff*(w-off)^2) [50]; u = ssp(ea@m1w + m1b) [128];
// Wf = (u@m2w + m2b)*C; msg = hx[row]*Wf; atomicAdd(agg[col], msg).
// Thread t owns column t: m1w[:,t] and m2w[:,t] in registers.
#define EPG 4
__global__ __launch_bounds__(256, 2) void edge_kernel(
        const float* __restrict__ ew, const float* __restrict__ cenv,
        const int* __restrict__ row, const int* __restrict__ col,
        const float* __restrict__ m1w, const float* __restrict__ m1b,
        const float* __restrict__ m2w, const float* __restrict__ m2b,
        const float* __restrict__ hx, float* __restrict__ agg, int E) {
    __shared__ __align__(16) float ea_sm[2][EPG][52];
    __shared__ __align__(16) float u_sm[2][EPG][HD];
    const int tid = threadIdx.x;
    const int t = tid & 127, grp = tid >> 7;

    float m1_r[52];
    #pragma unroll
    for (int g = 0; g < NGAUSS; ++g) m1_r[g] = m1w[g*HD + t];
    m1_r[50] = 0.0f; m1_r[51] = 0.0f;
    float m2_r[HD];
    #pragma unroll
    for (int k = 0; k < HD; ++k) m2_r[k] = m2w[k*HD + t];
    const float b1 = m1b[t], b2 = m2b[t];

    const float step = 10.0f / 49.0f;
    const float coeff = -0.5f / (step * step);

    for (int base = blockIdx.x * (2*EPG); base < E; base += gridDim.x * (2*EPG)) {
        // Phase A: cooperative gaussian smearing for 8 edges (2 grp x 4)
        #pragma unroll
        for (int s = 0; s < 2; ++s) {
            int idx = tid + 256 * s;
            if (idx < 2*EPG*52) {
                int g2 = idx / (EPG*52), rem = idx % (EPG*52);
                int e = rem / 52, gg = rem % 52;
                int eid = base + g2*EPG + e;
                float val = 0.0f;
                if (gg < NGAUSS && eid < E) {
                    float w = ew[eid];
                    float d = w - (float)gg * step;
                    val = __expf(coeff * d * d);
                }
                ea_sm[g2][e][gg] = val;
            }
        }
        __syncthreads();

        // Phase B: u = ssp(ea @ m1w + m1b)
        #pragma unroll
        for (int e = 0; e < EPG; ++e) {
            float acc = b1;
            const float4* eav = reinterpret_cast<const float4*>(ea_sm[grp][e]);
            #pragma unroll
            for (int q = 0; q < 13; ++q) {
                float4 v = eav[q];
                acc += v.x * m1_r[4*q+0] + v.y * m1_r[4*q+1]
                     + v.z * m1_r[4*q+2] + v.w * m1_r[4*q+3];
            }
            u_sm[grp][e][t] = ssp_f(acc);
        }
        __syncthreads();

        // Phase C: Wf = u @ m2w + m2b
        float acc[EPG];
        #pragma unroll
        for (int e = 0; e < EPG; ++e) acc[e] = b2;
        #pragma unroll
        for (int q = 0; q < 32; ++q) {
            #pragma unroll
            for (int e = 0; e < EPG; ++e) {
                float4 v = reinterpret_cast<const float4*>(u_sm[grp][e])[q];
                acc[e] += v.x * m2_r[4*q+0] + v.y * m2_r[4*q+1]
                        + v.z * m2_r[4*q+2] + v.w * m2_r[4*q+3];
            }
        }

        // Phase D: gather, modulate, scatter-add
        #pragma unroll
        for (int e = 0; e < EPG; ++e) {
            int eid = base + grp*EPG + e;
            if (eid < E) {
                int r = row[eid], c = col[eid];
                float msg = hx[r*HD + t] * acc[e] * cenv[eid];
                atomicAdd(&agg[c*HD + t], msg);
            }
        }
        __syncthreads();
    }
}

// ---------------- mean pool over graphs ----------------
__global__ void pool_kernel(const float* __restrict__ h1, const int* __restrict__ batch,
                            float* __restrict__ gsum, float* __restrict__ gcnt, int N) {
    __shared__ float pool[NGRAPH][HD];
    __shared__ float cnt[NGRAPH];
    const int t = threadIdx.x;
    #pragma unroll
    for (int g = 0; g < NGRAPH; ++g) pool[g][t] = 0.0f;
    if (t < NGRAPH) cnt[t] = 0.0f;
    __syncthreads();
    int chunk = (N + gridDim.x - 1) / gridDim.x;
    int n0 = blockIdx.x * chunk;
    int n1 = min(N, n0 + chunk);
    for (int n = n0; n < n1; ++n) {
        int b = batch[n];
        pool[b][t] += h1[n*HD + t];
        if (t == 0) cnt[b] += 1.0f;
    }
    __syncthreads();
    #pragma unroll
    for (int g = 0; g < NGRAPH; ++g) atomicAdd(&gsum[g*HD + t], pool[g][t]);
    if (t < NGRAPH) atomicAdd(&gcnt[t], cnt[t]);
}

// ---------------- head: graph_emb, h2 = relu(ge@lin1+b1), out = h2@lin2+b2 ----------------
__global__ void finalize_kernel(const float* __restrict__ gsum, const float* __restrict__ gcnt,
                                const float* __restrict__ l1w, const float* __restrict__ l1b,
                                const float* __restrict__ l2w, const float* __restrict__ l2b,
                                float* __restrict__ d_out) {
    __shared__ float ge[HD];
    __shared__ float h2[HD];
    const int g = blockIdx.x, t = threadIdx.x;
    float cnt = fmaxf(gcnt[g], 1.0f);
    float v = gsum[g*HD + t] / cnt;
    d_out[g*HD + t] = v;   // graph_emb output
    ge[t] = v;
    __syncthreads();
    float acc = l1b[t];
    #pragma unroll 8
    for (int k = 0; k < HD; ++k) acc += ge[k] * l1w[k*HD + t];
    h2[t] = fmaxf(acc, 0.0f);
    __syncthreads();
    if (t < NCLS) {
        float o = l2b[t];
        #pragma unroll 8
        for (int k = 0; k < HD; ++k) o += h2[k] * l2w[k*NCLS + t];
        d_out[NGRAPH*HD + g*NCLS + t] = o;
    }
}

extern "C" void kernel_launch(void* const* d_in, const int* in_sizes, int n_in,
                              void* d_out, int out_size, void* d_ws, size_t ws_size,
                              hipStream_t stream) {
    const float* x     = (const float*)d_in[0];
    const float* pos   = (const float*)d_in[1];
    const int*   eidx  = (const int*)d_in[2];
    const int*   batch = (const int*)d_in[3];
    const float* emb_w = (const float*)d_in[4];
    const float* emb_b = (const float*)d_in[5];
    const float* m1w   = (const float*)d_in[6];
    const float* m1b   = (const float*)d_in[7];
    const float* m2w   = (const float*)d_in[8];
    const float* m2b   = (const float*)d_in[9];
    const float* c1w   = (const float*)d_in[10];
    const float* c2w   = (const float*)d_in[11];
    const float* c2b   = (const float*)d_in[12];
    const float* lw    = (const float*)d_in[13];
    const float* lb    = (const float*)d_in[14];
    const float* l1w   = (const float*)d_in[15];
    const float* l1b   = (const float*)d_in[16];
    const float* l2w   = (const float*)d_in[17];
    const float* l2b   = (const float*)d_in[18];

    const int N = in_sizes[0] / 21;
    const int E = in_sizes[2] / 2;
    const int* row = eidx;
    const int* col = eidx + E;

    float* ws   = (float*)d_ws;
    float* ew   = ws;                 // E
    float* cenv = ew + E;             // E
    float* h    = cenv + E;           // N*128
    float* hx   = h + (size_t)N*HD;   // N*128  (reused as tmp and h1)
    float* agg  = hx + (size_t)N*HD;  // N*128
    float* gsum = agg + (size_t)N*HD; // 2048
    float* gcnt = gsum + NGRAPH*HD;   // 16

    geom_kernel<<<(E + 255)/256, 256, 0, stream>>>(pos, row, col, ew, cenv, E);
    embed_kernel<<<(N*HD + 255)/256, 256, 0, stream>>>(x, emb_w, emb_b, h, N);

    for (int l = 0; l < NLAYER; ++l) {
        // hx = h @ conv1_w (no bias)
        gemv128_kernel<0, false, false><<<512, 256, 0, stream>>>(h, c1w + l*HD*HD, nullptr, hx, N);
        hipMemsetAsync(agg, 0, (size_t)N*HD*sizeof(float), stream);
        edge_kernel<<<1024, 256, 0, stream>>>(ew, cenv, row, col,
                                              m1w + l*NGAUSS*HD, m1b + l*HD,
                                              m2w + l*HD*HD, m2b + l*HD,
                                              hx, agg, E);
        // tmp = ssp(agg @ conv2_w + conv2_b)    (into hx)
        gemv128_kernel<1, true, false><<<512, 256, 0, stream>>>(agg, c2w + l*HD*HD, c2b + l*HD, hx, N);
        // h = h + tmp @ lin_w + lin_b
        gemv128_kernel<0, true, true><<<512, 256, 0, stream>>>(hx, lw + l*HD*HD, lb + l*HD, h, N);
    }

    // h1 = relu(h @ lin1 + b1) into hx
    gemv128_kernel<2, true, false><<<512, 256, 0, stream>>>(h, l1w, l1b, hx, N);
    hipMemsetAsync(gsum, 0, (NGRAPH*HD + NGRAPH)*sizeof(float), stream);
    pool_kernel<<<256, 128, 0, stream>>>(hx, batch, gsum, gcnt, N);
    finalize_kernel<<<NGRAPH, 128, 0, stream>>>(gsum, gcnt, l1w, l1b, l2w, l2b, (float*)d_out);
}

// Round 2
// 24566.660 us; speedup vs baseline: 2.7787x; 2.7787x over previous
//
#include <hip/hip_runtime.h>
#include <hip/hip_bf16.h>

#define HD 128
#define NGAUSS 50
#define NLAYER 6
#define NGRAPH 16
#define NCLS 97
#define EPB 4   // edges per batch in fused conv

__device__ __forceinline__ float ssp_f(float x) {
    // softplus(x) - log(2), numerically stable
    return fmaxf(x, 0.0f) + log1pf(__expf(-fabsf(x))) - 0.69314718055994531f;
}

// ================= CSR build (once per call; edge_index fixed across layers) ==========
__global__ void hist_kernel(const int* __restrict__ col, int* __restrict__ deg, int E) {
    int e = blockIdx.x * blockDim.x + threadIdx.x;
    if (e < E) atomicAdd(&deg[col[e]], 1);
}

// single-block exclusive scan over N node degrees -> rowp[N+1], cursor copy
__global__ void scan_kernel(const int* __restrict__ deg, int* __restrict__ rowp,
                            int* __restrict__ cursor, int N) {
    __shared__ int part[256];
    const int t = threadIdx.x;
    const int chunk = (N + 255) / 256;
    const int i0 = t * chunk, i1 = min(N, i0 + chunk);
    int s = 0;
    for (int i = i0; i < i1; ++i) s += deg[i];
    part[t] = s;
    __syncthreads();
    // Hillis-Steele inclusive scan
    for (int off = 1; off < 256; off <<= 1) {
        int v = part[t];
        int add = (t >= off) ? part[t - off] : 0;
        __syncthreads();
        part[t] = v + add;
        __syncthreads();
    }
    int run = (t == 0) ? 0 : part[t - 1];
    for (int i = i0; i < i1; ++i) {
        rowp[i] = run;
        cursor[i] = run;
        run += deg[i];
    }
    if (t == 255) rowp[N] = run;   // == E
}

// scatter edges into destination-sorted slots; precompute per-slot geometry
__global__ void fill_kernel(const int* __restrict__ row, const int* __restrict__ col,
                            const float* __restrict__ pos, int* __restrict__ cursor,
                            int* __restrict__ row_s, float* __restrict__ ew_s,
                            float* __restrict__ cenv_s, int E) {
    int e = blockIdx.x * blockDim.x + threadIdx.x;
    if (e >= E) return;
    int c = col[e], r = row[e];
    int slot = atomicAdd(&cursor[c], 1);
    row_s[slot] = r;
    float dx = pos[r*3+0] - pos[c*3+0];
    float dy = pos[r*3+1] - pos[c*3+1];
    float dz = pos[r*3+2] - pos[c*3+2];
    float w = sqrtf(dx*dx + dy*dy + dz*dz);
    ew_s[slot] = w;
    cenv_s[slot] = 0.5f * (cosf(w * 0.31415926535897931f) + 1.0f);  // pi/10
}

// ================= embedding =================
__global__ void embed_kernel(const float* __restrict__ x,
                             const float* __restrict__ emb_w, const float* __restrict__ emb_b,
                             float* __restrict__ h, int N) {
    int idx = blockIdx.x * blockDim.x + threadIdx.x;
    if (idx >= N * HD) return;
    int n = idx >> 7, t = idx & 127;
    float acc = emb_b[t];
    #pragma unroll
    for (int a = 0; a < 21; ++a) acc += x[n*21 + a] * emb_w[a*HD + t];
    h[idx] = acc;
}

// ================= generic 128x128 GEMV over rows =================
// ACT: 0 none, 1 shifted-softplus, 2 relu
template<int ACT, bool BIAS, bool RES>
__global__ __launch_bounds__(256) void gemv128_kernel(
        const float* __restrict__ in, const float* __restrict__ W,
        const float* __restrict__ bias, float* __restrict__ out, int nrows) {
    __shared__ __align__(16) float rows_sm[2][4][HD];
    const int tid = threadIdx.x;
    const int t = tid & 127, grp = tid >> 7;

    float w_r[HD];
    #pragma unroll
    for (int k = 0; k < HD; ++k) w_r[k] = W[k*HD + t];
    const float bt = BIAS ? bias[t] : 0.0f;

    for (int base = blockIdx.x * 8; base < nrows; base += gridDim.x * 8) {
        const int n0 = base + grp * 4;
        __syncthreads();
        #pragma unroll
        for (int e = 0; e < 4; ++e) {
            int n = n0 + e;
            rows_sm[grp][e][t] = (n < nrows) ? in[n*HD + t] : 0.0f;
        }
        __syncthreads();

        float acc[4] = {0.f, 0.f, 0.f, 0.f};
        #pragma unroll
        for (int q = 0; q < 32; ++q) {
            #pragma unroll
            for (int e = 0; e < 4; ++e) {
                float4 v = reinterpret_cast<const float4*>(rows_sm[grp][e])[q];
                acc[e] += v.x * w_r[4*q+0] + v.y * w_r[4*q+1]
                        + v.z * w_r[4*q+2] + v.w * w_r[4*q+3];
            }
        }
        #pragma unroll
        for (int e = 0; e < 4; ++e) {
            int n = n0 + e;
            if (n < nrows) {
                float v = acc[e] + bt;
                if (ACT == 1) v = ssp_f(v);
                if (ACT == 2) v = fmaxf(v, 0.0f);
                if (RES) v += out[n*HD + t];
                out[n*HD + t] = v;
            }
        }
    }
}

// ================= fused per-node convolution (CSR, no atomics) =================
// Block = 128 threads = one node at a time (grid-stride). Thread t owns column t.
// Per 4-edge batch: Gaussian smearing (coop) -> u=ssp(ea@m1w+b1) -> Wf=u@m2w+b2
// -> acc[t] += hx[row]*Wf*C. Aggregate kept in registers; one coalesced store.
__global__ __launch_bounds__(128, 2) void conv_kernel(
        const int* __restrict__ rowp, const int* __restrict__ row_s,
        const float* __restrict__ ew_s, const float* __restrict__ cenv_s,
        const float* __restrict__ m1w, const float* __restrict__ m1b,
        const float* __restrict__ m2w, const float* __restrict__ m2b,
        const float* __restrict__ hx, float* __restrict__ agg, int N) {
    __shared__ __align__(16) float ea_sm[EPB][52];
    __shared__ __align__(16) float u_sm[EPB][HD];
    const int t = threadIdx.x;

    float m1_r[52];
    #pragma unroll
    for (int g = 0; g < NGAUSS; ++g) m1_r[g] = m1w[g*HD + t];
    m1_r[50] = 0.0f; m1_r[51] = 0.0f;
    float m2_r[HD];
    #pragma unroll
    for (int k = 0; k < HD; ++k) m2_r[k] = m2w[k*HD + t];
    const float b1 = m1b[t], b2 = m2b[t];

    const float step = 10.0f / 49.0f;
    const float coeff = -0.5f / (step * step);

    for (int n = blockIdx.x; n < N; n += gridDim.x) {
        const int s0 = rowp[n], s1 = rowp[n + 1];
        float acc = 0.0f;

        for (int p = s0; p < s1; p += EPB) {
            // ---- Phase A: cooperative Gaussian smearing for 4 edges (208 entries) ----
            #pragma unroll
            for (int it = 0; it < 2; ++it) {
                int idx = t + 128 * it;
                if (idx < EPB * 52) {
                    int e = idx / 52, gg = idx % 52;
                    int slot = p + e;
                    float val = 0.0f;
                    if (gg < NGAUSS && slot < s1) {
                        float w = ew_s[slot];
                        float d = w - (float)gg * step;
                        val = __expf(coeff * d * d);
                    }
                    ea_sm[e][gg] = val;
                }
            }
            __syncthreads();

            // issue the hx gathers + cutoff loads early (hide global latency under B+C)
            float hxv[EPB], cv[EPB];
            #pragma unroll
            for (int e = 0; e < EPB; ++e) {
                int slot = p + e;
                bool valid = slot < s1;
                hxv[e] = valid ? hx[(size_t)row_s[slot] * HD + t] : 0.0f;
                cv[e]  = valid ? cenv_s[slot] : 0.0f;
            }

            // ---- Phase B: u = ssp(ea @ m1w + b1) ----
            float ub[EPB];
            #pragma unroll
            for (int e = 0; e < EPB; ++e) ub[e] = b1;
            #pragma unroll
            for (int q = 0; q < 13; ++q) {
                #pragma unroll
                for (int e = 0; e < EPB; ++e) {
                    float4 v = reinterpret_cast<const float4*>(ea_sm[e])[q];
                    ub[e] += v.x * m1_r[4*q+0] + v.y * m1_r[4*q+1]
                           + v.z * m1_r[4*q+2] + v.w * m1_r[4*q+3];
                }
            }
            #pragma unroll
            for (int e = 0; e < EPB; ++e) u_sm[e][t] = ssp_f(ub[e]);
            __syncthreads();

            // ---- Phase C: Wf = u @ m2w + b2; acc += hx*Wf*C ----
            float a2[EPB];
            #pragma unroll
            for (int e = 0; e < EPB; ++e) a2[e] = b2;
            #pragma unroll
            for (int q = 0; q < 32; ++q) {
                #pragma unroll
                for (int e = 0; e < EPB; ++e) {
                    float4 v = reinterpret_cast<const float4*>(u_sm[e])[q];
                    a2[e] += v.x * m2_r[4*q+0] + v.y * m2_r[4*q+1]
                           + v.z * m2_r[4*q+2] + v.w * m2_r[4*q+3];
                }
            }
            #pragma unroll
            for (int e = 0; e < EPB; ++e) acc += hxv[e] * a2[e] * cv[e];
            __syncthreads();   // protect ea_sm/u_sm before next batch
        }

        agg[(size_t)n * HD + t] = acc;
    }
}

// ================= mean pool over graphs =================
__global__ void pool_kernel(const float* __restrict__ h1, const int* __restrict__ batch,
                            float* __restrict__ gsum, float* __restrict__ gcnt, int N) {
    __shared__ float pool[NGRAPH][HD];
    __shared__ float cnt[NGRAPH];
    const int t = threadIdx.x;
    #pragma unroll
    for (int g = 0; g < NGRAPH; ++g) pool[g][t] = 0.0f;
    if (t < NGRAPH) cnt[t] = 0.0f;
    __syncthreads();
    int chunk = (N + gridDim.x - 1) / gridDim.x;
    int n0 = blockIdx.x * chunk;
    int n1 = min(N, n0 + chunk);
    for (int n = n0; n < n1; ++n) {
        int b = batch[n];
        pool[b][t] += h1[n*HD + t];
        if (t == 0) cnt[b] += 1.0f;
    }
    __syncthreads();
    #pragma unroll
    for (int g = 0; g < NGRAPH; ++g) atomicAdd(&gsum[g*HD + t], pool[g][t]);
    if (t < NGRAPH) atomicAdd(&gcnt[t], cnt[t]);
}

// ================= head =================
__global__ void finalize_kernel(const float* __restrict__ gsum, const float* __restrict__ gcnt,
                                const float* __restrict__ l1w, const float* __restrict__ l1b,
                                const float* __restrict__ l2w, const float* __restrict__ l2b,
                                float* __restrict__ d_out) {
    __shared__ float ge[HD];
    __shared__ float h2[HD];
    const int g = blockIdx.x, t = threadIdx.x;
    float cnt = fmaxf(gcnt[g], 1.0f);
    float v = gsum[g*HD + t] / cnt;
    d_out[g*HD + t] = v;   // graph_emb output
    ge[t] = v;
    __syncthreads();
    float acc = l1b[t];
    #pragma unroll 8
    for (int k = 0; k < HD; ++k) acc += ge[k] * l1w[k*HD + t];
    h2[t] = fmaxf(acc, 0.0f);
    __syncthreads();
    if (t < NCLS) {
        float o = l2b[t];
        #pragma unroll 8
        for (int k = 0; k < HD; ++k) o += h2[k] * l2w[k*NCLS + t];
        d_out[NGRAPH*HD + g*NCLS + t] = o;
    }
}

extern "C" void kernel_launch(void* const* d_in, const int* in_sizes, int n_in,
                              void* d_out, int out_size, void* d_ws, size_t ws_size,
                              hipStream_t stream) {
    const float* x     = (const float*)d_in[0];
    const float* pos   = (const float*)d_in[1];
    const int*   eidx  = (const int*)d_in[2];
    const int*   batch = (const int*)d_in[3];
    const float* emb_w = (const float*)d_in[4];
    const float* emb_b = (const float*)d_in[5];
    const float* m1w   = (const float*)d_in[6];
    const float* m1b   = (const float*)d_in[7];
    const float* m2w   = (const float*)d_in[8];
    const float* m2b   = (const float*)d_in[9];
    const float* c1w   = (const float*)d_in[10];
    const float* c2w   = (const float*)d_in[11];
    const float* c2b   = (const float*)d_in[12];
    const float* lw    = (const float*)d_in[13];
    const float* lb    = (const float*)d_in[14];
    const float* l1w   = (const float*)d_in[15];
    const float* l1b   = (const float*)d_in[16];
    const float* l2w   = (const float*)d_in[17];
    const float* l2b   = (const float*)d_in[18];

    const int N = in_sizes[0] / 21;
    const int E = in_sizes[2] / 2;
    const int* row = eidx;
    const int* col = eidx + E;

    // ---- workspace layout ----
    char* wsb = (char*)d_ws;
    int*   deg    = (int*)wsb;                          wsb += (size_t)N * sizeof(int);
    int*   cursor = (int*)wsb;                          wsb += (size_t)N * sizeof(int);
    int*   rowp   = (int*)wsb;                          wsb += (size_t)(N + 1) * sizeof(int);
    int*   row_s  = (int*)wsb;                          wsb += (size_t)E * sizeof(int);
    float* ew_s   = (float*)wsb;                        wsb += (size_t)E * sizeof(float);
    float* cenv_s = (float*)wsb;                        wsb += (size_t)E * sizeof(float);
    float* h      = (float*)wsb;                        wsb += (size_t)N * HD * sizeof(float);
    float* hx     = (float*)wsb;                        wsb += (size_t)N * HD * sizeof(float);
    float* agg    = (float*)wsb;                        wsb += (size_t)N * HD * sizeof(float);
    float* gsum   = (float*)wsb;                        wsb += NGRAPH * HD * sizeof(float);
    float* gcnt   = (float*)wsb;

    // ---- CSR build (edge_index constant across layers) ----
    hipMemsetAsync(deg, 0, (size_t)N * sizeof(int), stream);
    hist_kernel<<<(E + 255)/256, 256, 0, stream>>>(col, deg, E);
    scan_kernel<<<1, 256, 0, stream>>>(deg, rowp, cursor, N);
    fill_kernel<<<(E + 255)/256, 256, 0, stream>>>(row, col, pos, cursor,
                                                   row_s, ew_s, cenv_s, E);

    embed_kernel<<<(N*HD + 255)/256, 256, 0, stream>>>(x, emb_w, emb_b, h, N);

    for (int l = 0; l < NLAYER; ++l) {
        // hx = h @ conv1_w (no bias)
        gemv128_kernel<0, false, false><<<512, 256, 0, stream>>>(h, c1w + l*HD*HD, nullptr, hx, N);
        // agg[n] = sum over incoming edges of hx[row]*Wf*C  (fused, no atomics)
        conv_kernel<<<2048, 128, 0, stream>>>(rowp, row_s, ew_s, cenv_s,
                                              m1w + l*NGAUSS*HD, m1b + l*HD,
                                              m2w + l*HD*HD, m2b + l*HD,
                                              hx, agg, N);
        // tmp = ssp(agg @ conv2_w + conv2_b)    (into hx)
        gemv128_kernel<1, true, false><<<512, 256, 0, stream>>>(agg, c2w + l*HD*HD, c2b + l*HD, hx, N);
        // h = h + tmp @ lin_w + lin_b
        gemv128_kernel<0, true, true><<<512, 256, 0, stream>>>(hx, lw + l*HD*HD, lb + l*HD, h, N);
    }

    // h1 = relu(h @ lin1 + b1) into hx
    gemv128_kernel<2, true, false><<<512, 256, 0, stream>>>(h, l1w, l1b, hx, N);
    hipMemsetAsync(gsum, 0, (NGRAPH*HD + NGRAPH)*sizeof(float), stream);
    pool_kernel<<<256, 128, 0, stream>>>(hx, batch, gsum, gcnt, N);
    finalize_kernel<<<NGRAPH, 128, 0, stream>>>(gsum, gcnt, l1w, l1b, l2w, l2b, (float*)d_out);
}

// Round 3
// 3052.244 us; speedup vs baseline: 22.3649x; 8.0487x over previous
//
#include <hip/hip_runtime.h>
#include <hip/hip_bf16.h>

#define HD 128
#define NGAUSS 50
#define NLAYER 6
#define NGRAPH 16
#define NCLS 97

typedef __attribute__((ext_vector_type(8))) short bf16x8;
typedef __attribute__((ext_vector_type(4))) float f32x4;
typedef __attribute__((ext_vector_type(8))) ushort u16x8;
typedef __attribute__((ext_vector_type(4))) ushort u16x4;

__device__ __forceinline__ float ssp_f(float x) {
    return fmaxf(x, 0.0f) + log1pf(__expf(-fabsf(x))) - 0.69314718055994531f;
}
__device__ __forceinline__ ushort f2bf(float f) {   // RNE f32->bf16
    uint u = __float_as_uint(f);
    return (ushort)((u + 0x7FFFu + ((u >> 16) & 1u)) >> 16);
}
__device__ __forceinline__ float bf2f(ushort s) {
    return __uint_as_float(((uint)s) << 16);
}

// ================= CSR build =================
__global__ void hist_kernel(const int* __restrict__ col, int* __restrict__ deg, int E) {
    int e = blockIdx.x * blockDim.x + threadIdx.x;
    if (e < E) atomicAdd(&deg[col[e]], 1);
}

__global__ void scan_kernel(const int* __restrict__ deg, int* __restrict__ rowp,
                            int* __restrict__ cursor, int N) {
    __shared__ int part[256];
    const int t = threadIdx.x;
    const int chunk = (N + 255) / 256;
    const int i0 = t * chunk, i1 = min(N, i0 + chunk);
    int s = 0;
    for (int i = i0; i < i1; ++i) s += deg[i];
    part[t] = s;
    __syncthreads();
    for (int off = 1; off < 256; off <<= 1) {
        int v = part[t];
        int add = (t >= off) ? part[t - off] : 0;
        __syncthreads();
        part[t] = v + add;
        __syncthreads();
    }
    int run = (t == 0) ? 0 : part[t - 1];
    for (int i = i0; i < i1; ++i) {
        rowp[i] = run; cursor[i] = run; run += deg[i];
    }
    if (t == 255) rowp[N] = run;
}

__global__ void fill_kernel(const int* __restrict__ row, const int* __restrict__ col,
                            const float* __restrict__ pos, int* __restrict__ cursor,
                            int* __restrict__ row_s, float* __restrict__ ew_s,
                            float* __restrict__ cenv_s, int E) {
    int e = blockIdx.x * blockDim.x + threadIdx.x;
    if (e >= E) return;
    int c = col[e], r = row[e];
    int slot = atomicAdd(&cursor[c], 1);
    row_s[slot] = r;
    float dx = pos[r*3+0] - pos[c*3+0];
    float dy = pos[r*3+1] - pos[c*3+1];
    float dz = pos[r*3+2] - pos[c*3+2];
    float w = sqrtf(dx*dx + dy*dy + dz*dz);
    ew_s[slot] = w;
    cenv_s[slot] = 0.5f * (cosf(w * 0.31415926535897931f) + 1.0f);
}

// ================= weight prep: transpose + bf16 (hi/lo split for node mats) ========
__global__ void prep_kernel(const float* __restrict__ m1w, const float* __restrict__ c1w,
                            const float* __restrict__ c2w, const float* __restrict__ lw,
                            const float* __restrict__ l1w, const float* __restrict__ m2w,
                            ushort* __restrict__ m1T, ushort* __restrict__ nodeThi,
                            ushort* __restrict__ nodeTlo, ushort* __restrict__ m2T) {
    int idx = blockIdx.x * blockDim.x + threadIdx.x;
    const int S1 = 6*128*64, S2 = 19*128*128, S3 = 6*128*128;
    if (idx < S1) {
        int l = idx / 8192, r = idx % 8192, c = r / 64, k = r % 64;
        float v = (k < NGAUSS) ? m1w[(size_t)l*NGAUSS*128 + k*128 + c] : 0.0f;
        m1T[(size_t)l*8192 + c*64 + k] = f2bf(v);
    } else if (idx < S1 + S2) {
        int j = idx - S1;
        int m = j / 16384, r = j % 16384, c = r / 128, k = r % 128;
        const float* src;
        if (m < 6)       src = c1w + (size_t)m*16384;
        else if (m < 12) src = c2w + (size_t)(m-6)*16384;
        else if (m < 18) src = lw  + (size_t)(m-12)*16384;
        else             src = l1w;
        float v = src[k*128 + c];
        ushort hi = f2bf(v);
        nodeThi[(size_t)m*16384 + c*128 + k] = hi;
        nodeTlo[(size_t)m*16384 + c*128 + k] = f2bf(v - bf2f(hi));
    } else if (idx < S1 + S2 + S3) {
        int j = idx - S1 - S2;
        int l = j / 16384, r = j % 16384, c = r / 128, k = r % 128;
        m2T[(size_t)l*16384 + c*128 + k] = f2bf(m2w[(size_t)l*16384 + k*128 + c]);
    }
}

// ================= embedding =================
__global__ void embed_kernel(const float* __restrict__ x,
                             const float* __restrict__ emb_w, const float* __restrict__ emb_b,
                             float* __restrict__ h, int N) {
    int idx = blockIdx.x * blockDim.x + threadIdx.x;
    if (idx >= N * HD) return;
    int n = idx >> 7, t = idx & 127;
    float acc = emb_b[t];
    #pragma unroll
    for (int a = 0; a < 21; ++a) acc += x[n*21 + a] * emb_w[a*HD + t];
    h[idx] = acc;
}

// ================= unified MFMA GEMM =================
// C[M,128] = epilogue(A[M,K] @ B[K,128])
// B prepped transposed: BT[c][k] bf16. BSPLIT: B = BThi + BTlo (hi/lo bf16 split).
// ASRC: 0 = f32 rows, 1 = bf16 rows, 2 = generate Gaussian ea from ew_s (K=64)
// EPI:  0 = store f32 (no bias)                      [conv1 -> hx]
//       1 = bias+ssp -> store bf16                   [GEMM1 -> u ; conv2 -> tmpb]
//       2 = bias -> store bf16                       [GEMM2 -> Wf]
//       3 = bias + residual add into f32 dst         [lin -> h]
//       4 = bias + relu -> store f32                 [lin1 -> h1]
template<int K, int ASRC, int EPI, bool BSPLIT>
__global__ __launch_bounds__(256, 2) void gemm_kernel(
        const void* __restrict__ AsrcV, const ushort* __restrict__ BThi,
        const ushort* __restrict__ BTlo, const float* __restrict__ bias,
        float* __restrict__ fdst, ushort* __restrict__ bdst, int mtiles) {
    constexpr int BKW = BSPLIT ? 64 : K;      // staged B chunk width
    __shared__ ushort A_lds[128 * K];
    __shared__ ushort B_lds[128 * BKW];
    char* Ab = (char*)A_lds;
    char* Bb = (char*)B_lds;
    const int tid  = threadIdx.x;
    const int lane = tid & 63;
    const int wave = tid >> 6;
    const int l15  = lane & 15;
    const int kgrp = (lane >> 4) * 8;

    if (!BSPLIT) {  // resident B: stage once
        constexpr int PASSES = 128 * K / (256 * 8);
        #pragma unroll
        for (int p = 0; p < PASSES; ++p) {
            int rr, k8;
            if (K == 128) { rr = p * 16 + (tid >> 4); k8 = (tid & 15) * 8; }
            else          { rr = p * 32 + (tid >> 3); k8 = (tid & 7) * 8; }
            u16x8 v = *reinterpret_cast<const u16x8*>(&BThi[(size_t)rr * K + k8]);
            *reinterpret_cast<u16x8*>(&Bb[rr*(2*K) + ((2*k8) ^ ((rr & 7) << 4))]) = v;
        }
        __syncthreads();
    }

    for (int mt = blockIdx.x; mt < mtiles; mt += gridDim.x) {
        __syncthreads();  // previous tile's LDS reads complete
        // ---- stage A (swizzled bf16) ----
        if (ASRC == 0) {
            const float* A = (const float*)AsrcV;
            #pragma unroll
            for (int p = 0; p < 16; ++p) {
                int rr = p * 8 + (tid >> 5);
                int k4 = (tid & 31) * 4;
                f32x4 v = *reinterpret_cast<const f32x4*>(&A[(size_t)(mt*128 + rr)*K + k4]);
                u16x4 b;
                b.x = f2bf(v.x); b.y = f2bf(v.y); b.z = f2bf(v.z); b.w = f2bf(v.w);
                *reinterpret_cast<u16x4*>(&Ab[rr*(2*K) + ((2*k4) ^ ((rr & 7) << 4))]) = b;
            }
        } else if (ASRC == 1) {
            const ushort* A = (const ushort*)AsrcV;
            #pragma unroll
            for (int p = 0; p < (K == 128 ? 8 : 4); ++p) {
                int rr, k8;
                if (K == 128) { rr = p * 16 + (tid >> 4); k8 = (tid & 15) * 8; }
                else          { rr = p * 32 + (tid >> 3); k8 = (tid & 7) * 8; }
                u16x8 v = *reinterpret_cast<const u16x8*>(&A[(size_t)(mt*128 + rr)*K + k8]);
                *reinterpret_cast<u16x8*>(&Ab[rr*(2*K) + ((2*k8) ^ ((rr & 7) << 4))]) = v;
            }
        } else {  // ASRC == 2: generate Gaussian smearing rows (K == 64)
            const float* ew = (const float*)AsrcV;
            const float step = 10.0f / 49.0f;
            const float coeff = -0.5f / (step * step);
            #pragma unroll
            for (int p = 0; p < 4; ++p) {
                int rr = p * 32 + (tid >> 3);
                int k8 = (tid & 7) * 8;
                float w = ew[mt*128 + rr];
                u16x8 v;
                #pragma unroll
                for (int j = 0; j < 8; ++j) {
                    int k = k8 + j;
                    float d = w - (float)k * step;
                    float g = (k < NGAUSS) ? __expf(coeff * d * d) : 0.0f;
                    v[j] = f2bf(g);
                }
                *reinterpret_cast<u16x8*>(&Ab[rr*(2*K) + ((2*k8) ^ ((rr & 7) << 4))]) = v;
            }
        }

        f32x4 acc[2][8];
        #pragma unroll
        for (int i = 0; i < 2; ++i)
            #pragma unroll
            for (int j = 0; j < 8; ++j) { acc[i][j].x=0.f; acc[i][j].y=0.f; acc[i][j].z=0.f; acc[i][j].w=0.f; }

        const int rbase = wave * 32;

        if (!BSPLIT) {
            __syncthreads();
            #pragma unroll
            for (int ks = 0; ks < K/32; ++ks) {
                int k = ks*32 + kgrp;
                bf16x8 af[2];
                #pragma unroll
                for (int rt = 0; rt < 2; ++rt) {
                    int r = rbase + rt*16 + l15;
                    af[rt] = *reinterpret_cast<const bf16x8*>(&Ab[r*(2*K) + ((2*k) ^ ((r & 7) << 4))]);
                }
                #pragma unroll
                for (int cb = 0; cb < 8; ++cb) {
                    int c = cb*16 + l15;
                    bf16x8 bv = *reinterpret_cast<const bf16x8*>(&Bb[c*(2*K) + ((2*k) ^ ((c & 7) << 4))]);
                    acc[0][cb] = __builtin_amdgcn_mfma_f32_16x16x32_bf16(af[0], bv, acc[0][cb], 0, 0, 0);
                    acc[1][cb] = __builtin_amdgcn_mfma_f32_16x16x32_bf16(af[1], bv, acc[1][cb], 0, 0, 0);
                }
            }
        } else {
            #pragma unroll
            for (int part = 0; part < 2; ++part) {
                const ushort* BT = part ? BTlo : BThi;
                #pragma unroll
                for (int kh = 0; kh < K/64; ++kh) {
                    __syncthreads();   // prior round's B reads done; 1st round: A visible after next sync
                    #pragma unroll
                    for (int p = 0; p < 4; ++p) {
                        int rr = p * 32 + (tid >> 3);
                        int kk = (tid & 7) * 8;
                        u16x8 v = *reinterpret_cast<const u16x8*>(&BT[(size_t)rr*K + kh*64 + kk]);
                        *reinterpret_cast<u16x8*>(&Bb[rr*128 + ((2*kk) ^ ((rr & 7) << 4))]) = v;
                    }
                    __syncthreads();
                    #pragma unroll
                    for (int ks2 = 0; ks2 < 2; ++ks2) {
                        int ka = kh*64 + ks2*32 + kgrp;
                        int kb = ks2*32 + kgrp;
                        bf16x8 af[2];
                        #pragma unroll
                        for (int rt = 0; rt < 2; ++rt) {
                            int r = rbase + rt*16 + l15;
                            af[rt] = *reinterpret_cast<const bf16x8*>(&Ab[r*(2*K) + ((2*ka) ^ ((r & 7) << 4))]);
                        }
                        #pragma unroll
                        for (int cb = 0; cb < 8; ++cb) {
                            int c = cb*16 + l15;
                            bf16x8 bv = *reinterpret_cast<const bf16x8*>(&Bb[c*128 + ((2*kb) ^ ((c & 7) << 4))]);
                            acc[0][cb] = __builtin_amdgcn_mfma_f32_16x16x32_bf16(af[0], bv, acc[0][cb], 0, 0, 0);
                            acc[1][cb] = __builtin_amdgcn_mfma_f32_16x16x32_bf16(af[1], bv, acc[1][cb], 0, 0, 0);
                        }
                    }
                }
            }
        }

        // ---- epilogue ----
        float bcol[8];
        if (EPI != 0) {
            #pragma unroll
            for (int cb = 0; cb < 8; ++cb) bcol[cb] = bias[cb*16 + l15];
        }
        #pragma unroll
        for (int rt = 0; rt < 2; ++rt) {
            #pragma unroll
            for (int cb = 0; cb < 8; ++cb) {
                #pragma unroll
                for (int i = 0; i < 4; ++i) {
                    int row = mt*128 + rbase + rt*16 + (lane >> 4)*4 + i;
                    int col = cb*16 + l15;
                    size_t off = (size_t)row * HD + col;
                    float v = acc[rt][cb][i];
                    if (EPI == 0)      fdst[off] = v;
                    else if (EPI == 1) bdst[off] = f2bf(ssp_f(v + bcol[cb]));
                    else if (EPI == 2) bdst[off] = f2bf(v + bcol[cb]);
                    else if (EPI == 3) fdst[off] = fdst[off] + v + bcol[cb];
                    else               fdst[off] = fmaxf(v + bcol[cb], 0.0f);
                }
            }
        }
    }
}

// ================= streaming segment-sum (dest-sorted, no atomics) =================
// agg[n][t] = sum_{s in [rowp[n],rowp[n+1])} bf2f(Wf[s][t]) * cenv[s] * hx[row_s[s]][t]
__global__ void segsum_kernel(const ushort* __restrict__ Wf, const int* __restrict__ rowp,
                              const int* __restrict__ row_s, const float* __restrict__ cenv_s,
                              const float* __restrict__ hx, float* __restrict__ agg, int N) {
    const int n = blockIdx.x;
    if (n >= N) return;
    const int t = threadIdx.x;
    const int s0 = rowp[n], s1 = rowp[n + 1];
    float acc = 0.0f;
    for (int s = s0; s < s1; ++s) {
        float wf = bf2f(Wf[(size_t)s * HD + t]);
        acc += wf * cenv_s[s] * hx[(size_t)row_s[s] * HD + t];
    }
    agg[(size_t)n * HD + t] = acc;
}

// ================= mean pool =================
__global__ void pool_kernel(const float* __restrict__ h1, const int* __restrict__ batch,
                            float* __restrict__ gsum, float* __restrict__ gcnt, int N) {
    __shared__ float pool[NGRAPH][HD];
    __shared__ float cnt[NGRAPH];
    const int t = threadIdx.x;
    #pragma unroll
    for (int g = 0; g < NGRAPH; ++g) pool[g][t] = 0.0f;
    if (t < NGRAPH) cnt[t] = 0.0f;
    __syncthreads();
    int chunk = (N + gridDim.x - 1) / gridDim.x;
    int n0 = blockIdx.x * chunk, n1 = min(N, n0 + chunk);
    for (int n = n0; n < n1; ++n) {
        int b = batch[n];
        pool[b][t] += h1[(size_t)n * HD + t];
        if (t == 0) cnt[b] += 1.0f;
    }
    __syncthreads();
    #pragma unroll
    for (int g = 0; g < NGRAPH; ++g) atomicAdd(&gsum[g*HD + t], pool[g][t]);
    if (t < NGRAPH) atomicAdd(&gcnt[t], cnt[t]);
}

// ================= head =================
__global__ void finalize_kernel(const float* __restrict__ gsum, const float* __restrict__ gcnt,
                                const float* __restrict__ l1w, const float* __restrict__ l1b,
                                const float* __restrict__ l2w, const float* __restrict__ l2b,
                                float* __restrict__ d_out) {
    __shared__ float ge[HD];
    __shared__ float h2[HD];
    const int g = blockIdx.x, t = threadIdx.x;
    float cnt = fmaxf(gcnt[g], 1.0f);
    float v = gsum[g*HD + t] / cnt;
    d_out[g*HD + t] = v;
    ge[t] = v;
    __syncthreads();
    float acc = l1b[t];
    #pragma unroll 8
    for (int k = 0; k < HD; ++k) acc += ge[k] * l1w[k*HD + t];
    h2[t] = fmaxf(acc, 0.0f);
    __syncthreads();
    if (t < NCLS) {
        float o = l2b[t];
        #pragma unroll 8
        for (int k = 0; k < HD; ++k) o += h2[k] * l2w[k*NCLS + t];
        d_out[NGRAPH*HD + g*NCLS + t] = o;
    }
}

extern "C" void kernel_launch(void* const* d_in, const int* in_sizes, int n_in,
                              void* d_out, int out_size, void* d_ws, size_t ws_size,
                              hipStream_t stream) {
    const float* x     = (const float*)d_in[0];
    const float* pos   = (const float*)d_in[1];
    const int*   eidx  = (const int*)d_in[2];
    const int*   batch = (const int*)d_in[3];
    const float* emb_w = (const float*)d_in[4];
    const float* emb_b = (const float*)d_in[5];
    const float* m1w   = (const float*)d_in[6];
    const float* m1b   = (const float*)d_in[7];
    const float* m2w   = (const float*)d_in[8];
    const float* m2b   = (const float*)d_in[9];
    const float* c1w   = (const float*)d_in[10];
    const float* c2w   = (const float*)d_in[11];
    const float* c2b   = (const float*)d_in[12];
    const float* lw    = (const float*)d_in[13];
    const float* lb    = (const float*)d_in[14];
    const float* l1w   = (const float*)d_in[15];
    const float* l1b   = (const float*)d_in[16];
    const float* l2w   = (const float*)d_in[17];
    const float* l2b   = (const float*)d_in[18];

    const int N = in_sizes[0] / 21;          // 20000
    const int E = in_sizes[2] / 2;           // 640000
    const int* row = eidx;
    const int* col = eidx + E;
    const int NT   = (N + 127) / 128;        // 157 node M-tiles
    const int Npad = NT * 128;               // 20096
    const int ET   = E / 128;                // 5000 edge M-tiles

    // ---- workspace layout (256B aligned blocks) ----
    size_t off = 0;
    char* base = (char*)d_ws;
    auto alloc = [&](size_t bytes) -> void* {
        off = (off + 255) & ~(size_t)255;
        void* p = base + off;
        off += bytes;
        return p;
    };
    int*    deg     = (int*)alloc((size_t)N * 4);
    int*    cursor  = (int*)alloc((size_t)N * 4);
    int*    rowp    = (int*)alloc((size_t)(N + 1) * 4);
    int*    row_s   = (int*)alloc((size_t)E * 4);
    float*  ew_s    = (float*)alloc((size_t)E * 4);
    float*  cenv_s  = (float*)alloc((size_t)E * 4);
    float*  h       = (float*)alloc((size_t)Npad * HD * 4);
    float*  hx      = (float*)alloc((size_t)Npad * HD * 4);
    float*  agg     = (float*)alloc((size_t)Npad * HD * 4);
    float*  h1      = (float*)alloc((size_t)Npad * HD * 4);
    ushort* tmpb    = (ushort*)alloc((size_t)Npad * HD * 2);
    ushort* Wf      = (ushort*)alloc((size_t)E * HD * 2);      // u then Wf (aliased)
    ushort* m1T     = (ushort*)alloc((size_t)6 * 128 * 64 * 2);
    ushort* nodeThi = (ushort*)alloc((size_t)19 * 128 * 128 * 2);
    ushort* nodeTlo = (ushort*)alloc((size_t)19 * 128 * 128 * 2);
    ushort* m2T     = (ushort*)alloc((size_t)6 * 128 * 128 * 2);
    float*  gsum    = (float*)alloc((size_t)NGRAPH * HD * 4);
    float*  gcnt    = (float*)alloc((size_t)NGRAPH * 4);

    // ---- one-time per call: weight prep + CSR ----
    prep_kernel<<<1792, 256, 0, stream>>>(m1w, c1w, c2w, lw, l1w, m2w,
                                          m1T, nodeThi, nodeTlo, m2T);
    hipMemsetAsync(deg, 0, (size_t)N * 4, stream);
    hist_kernel<<<(E + 255)/256, 256, 0, stream>>>(col, deg, E);
    scan_kernel<<<1, 256, 0, stream>>>(deg, rowp, cursor, N);
    fill_kernel<<<(E + 255)/256, 256, 0, stream>>>(row, col, pos, cursor,
                                                   row_s, ew_s, cenv_s, E);
    embed_kernel<<<(N*HD + 255)/256, 256, 0, stream>>>(x, emb_w, emb_b, h, N);

    for (int l = 0; l < NLAYER; ++l) {
        const ushort* c1Thi = nodeThi + (size_t)l * 16384;
        const ushort* c1Tlo = nodeTlo + (size_t)l * 16384;
        const ushort* c2Thi = nodeThi + (size_t)(6 + l) * 16384;
        const ushort* c2Tlo = nodeTlo + (size_t)(6 + l) * 16384;
        const ushort* lThi  = nodeThi + (size_t)(12 + l) * 16384;
        const ushort* lTlo  = nodeTlo + (size_t)(12 + l) * 16384;

        // hx = h @ c1w   (no bias)
        gemm_kernel<128, 0, 0, true><<<NT, 256, 0, stream>>>(
            h, c1Thi, c1Tlo, nullptr, hx, nullptr, NT);
        // u = ssp(ea @ m1w + m1b)   (ea generated in staging)
        gemm_kernel<64, 2, 1, false><<<2500, 256, 0, stream>>>(
            ew_s, m1T + (size_t)l * 8192, nullptr, m1b + l*HD, nullptr, Wf, ET);
        // Wf = u @ m2w + m2b   (aliased in place)
        gemm_kernel<128, 1, 2, false><<<2500, 256, 0, stream>>>(
            Wf, m2T + (size_t)l * 16384, nullptr, m2b + l*HD, nullptr, Wf, ET);
        // agg[n] = sum_s Wf[s]*cenv[s]*hx[row_s[s]]
        segsum_kernel<<<N, HD, 0, stream>>>(Wf, rowp, row_s, cenv_s, hx, agg, N);
        // tmpb = bf16(ssp(agg @ c2w + c2b))
        gemm_kernel<128, 0, 1, true><<<NT, 256, 0, stream>>>(
            agg, c2Thi, c2Tlo, c2b + l*HD, nullptr, tmpb, NT);
        // h += tmpb @ lw + lb
        gemm_kernel<128, 1, 3, true><<<NT, 256, 0, stream>>>(
            tmpb, lThi, lTlo, lb + l*HD, h, nullptr, NT);
    }

    // h1 = relu(h @ lin1 + b1)
    gemm_kernel<128, 0, 4, true><<<NT, 256, 0, stream>>>(
        h, nodeThi + (size_t)18 * 16384, nodeTlo + (size_t)18 * 16384,
        l1b, h1, nullptr, NT);

    hipMemsetAsync(gsum, 0, (size_t)(NGRAPH*HD + NGRAPH) * 4, stream);
    pool_kernel<<<256, HD, 0, stream>>>(h1, batch, gsum, gcnt, N);
    finalize_kernel<<<NGRAPH, HD, 0, stream>>>(gsum, gcnt, l1w, l1b, l2w, l2b,
                                               (float*)d_out);
}

// Round 5
// 1360.295 us; speedup vs baseline: 50.1827x; 2.2438x over previous
//
#include <hip/hip_runtime.h>
#include <hip/hip_bf16.h>

#define HD 128
#define NGAUSS 50
#define NLAYER 6
#define NGRAPH 16
#define NCLS 97

typedef __attribute__((ext_vector_type(8))) short bf16x8;
typedef __attribute__((ext_vector_type(4))) float f32x4;
typedef __attribute__((ext_vector_type(8))) ushort u16x8;
typedef __attribute__((ext_vector_type(4))) ushort u16x4;

// fast shifted-softplus: softplus(x)-ln2 = max(x,0) + ln(0.5 + 0.5*exp(-|x|))
__device__ __forceinline__ float ssp_f(float x) {
    float e = __expf(-fabsf(x));
    return fmaxf(x, 0.0f) + __logf(0.5f + 0.5f * e);
}
__device__ __forceinline__ ushort f2bf(float f) {   // RNE f32->bf16
    uint u = __float_as_uint(f);
    return (ushort)((u + 0x7FFFu + ((u >> 16) & 1u)) >> 16);
}
__device__ __forceinline__ float bf2f(ushort s) {
    return __uint_as_float(((uint)s) << 16);
}

// ================= CSR build =================
__global__ void hist_kernel(const int* __restrict__ col, int* __restrict__ deg, int E) {
    int e = blockIdx.x * blockDim.x + threadIdx.x;
    if (e < E) atomicAdd(&deg[col[e]], 1);
}

__global__ void scan_kernel(const int* __restrict__ deg, int* __restrict__ rowp,
                            int* __restrict__ cursor, int N) {
    __shared__ int part[256];
    const int t = threadIdx.x;
    const int chunk = (N + 255) / 256;
    const int i0 = t * chunk, i1 = min(N, i0 + chunk);
    int s = 0;
    for (int i = i0; i < i1; ++i) s += deg[i];
    part[t] = s;
    __syncthreads();
    for (int off = 1; off < 256; off <<= 1) {
        int v = part[t];
        int add = (t >= off) ? part[t - off] : 0;
        __syncthreads();
        part[t] = v + add;
        __syncthreads();
    }
    int run = (t == 0) ? 0 : part[t - 1];
    for (int i = i0; i < i1; ++i) {
        rowp[i] = run; cursor[i] = run; run += deg[i];
    }
    if (t == 255) rowp[N] = run;
}

__global__ void fill_kernel(const int* __restrict__ row, const int* __restrict__ col,
                            const float* __restrict__ pos, int* __restrict__ cursor,
                            int* __restrict__ row_s, float* __restrict__ ew_s,
                            float* __restrict__ cenv_s, int E) {
    int e = blockIdx.x * blockDim.x + threadIdx.x;
    if (e >= E) return;
    int c = col[e], r = row[e];
    int slot = atomicAdd(&cursor[c], 1);
    row_s[slot] = r;
    float dx = pos[r*3+0] - pos[c*3+0];
    float dy = pos[r*3+1] - pos[c*3+1];
    float dz = pos[r*3+2] - pos[c*3+2];
    float w = sqrtf(dx*dx + dy*dy + dz*dz);
    ew_s[slot] = w;
    cenv_s[slot] = 0.5f * (cosf(w * 0.31415926535897931f) + 1.0f);
}

// ================= weight prep: transpose + bf16 (hi/lo split for node mats) ========
__global__ void prep_kernel(const float* __restrict__ m1w, const float* __restrict__ c1w,
                            const float* __restrict__ c2w, const float* __restrict__ lw,
                            const float* __restrict__ l1w, const float* __restrict__ m2w,
                            ushort* __restrict__ m1T, ushort* __restrict__ nodeThi,
                            ushort* __restrict__ nodeTlo, ushort* __restrict__ m2T) {
    int idx = blockIdx.x * blockDim.x + threadIdx.x;
    const int S1 = 6*128*64, S2 = 19*128*128, S3 = 6*128*128;
    if (idx < S1) {
        int l = idx / 8192, r = idx % 8192, c = r / 64, k = r % 64;
        float v = (k < NGAUSS) ? m1w[(size_t)l*NGAUSS*128 + k*128 + c] : 0.0f;
        m1T[(size_t)l*8192 + c*64 + k] = f2bf(v);
    } else if (idx < S1 + S2) {
        int j = idx - S1;
        int m = j / 16384, r = j % 16384, c = r / 128, k = r % 128;
        const float* src;
        if (m < 6)       src = c1w + (size_t)m*16384;
        else if (m < 12) src = c2w + (size_t)(m-6)*16384;
        else if (m < 18) src = lw  + (size_t)(m-12)*16384;
        else             src = l1w;
        float v = src[k*128 + c];
        ushort hi = f2bf(v);
        nodeThi[(size_t)m*16384 + c*128 + k] = hi;
        nodeTlo[(size_t)m*16384 + c*128 + k] = f2bf(v - bf2f(hi));
    } else if (idx < S1 + S2 + S3) {
        int j = idx - S1 - S2;
        int l = j / 16384, r = j % 16384, c = r / 128, k = r % 128;
        m2T[(size_t)l*16384 + c*128 + k] = f2bf(m2w[(size_t)l*16384 + k*128 + c]);
    }
}

// ================= embedding =================
__global__ void embed_kernel(const float* __restrict__ x,
                             const float* __restrict__ emb_w, const float* __restrict__ emb_b,
                             float* __restrict__ h, int N) {
    int idx = blockIdx.x * blockDim.x + threadIdx.x;
    if (idx >= N * HD) return;
    int n = idx >> 7, t = idx & 127;
    float acc = emb_b[t];
    #pragma unroll
    for (int a = 0; a < 21; ++a) acc += x[n*21 + a] * emb_w[a*HD + t];
    h[idx] = acc;
}

// ================= fused edge filter: Wf = (ssp(ea@m1w+b1)@m2w + b2)*cenv =========
// 256 threads, tile = 128 edges. LDS = 64 KB: A1 16K (ea tile, REUSED as m2T chunk
// after GEMM1) + B1 16K (m1T resident) + U 32K. u never touches HBM.
// ea is regenerated per layer from ew_s (cheap: ~8 VALU + 1 exp per element).
__global__ __launch_bounds__(256, 2) void efilter_kernel(
        const float* __restrict__ ew_s, const ushort* __restrict__ m1T,
        const ushort* __restrict__ m2T, const float* __restrict__ m1b,
        const float* __restrict__ m2b, const float* __restrict__ cenv_s,
        ushort* __restrict__ Wf, int mtiles) {
    __shared__ ushort A1[128 * 64];   // ea tile, then m2T chunk (B2)
    __shared__ ushort B1[128 * 64];   // m1T resident
    __shared__ ushort U [128 * 128];  // intermediate u (bf16)
    char* A1b = (char*)A1;
    char* B1b = (char*)B1;
    char* Ub  = (char*)U;
    const int tid  = threadIdx.x;
    const int lane = tid & 63;
    const int wave = tid >> 6;
    const int l15  = lane & 15;
    const int kgrp = (lane >> 4) * 8;
    const int rbase = wave * 32;

    // stage m1T resident ([col][k64], swizzled)
    #pragma unroll
    for (int p = 0; p < 4; ++p) {
        int rr = p * 32 + (tid >> 3);
        int k8 = (tid & 7) * 8;
        u16x8 v = *reinterpret_cast<const u16x8*>(&m1T[(size_t)rr * 64 + k8]);
        *reinterpret_cast<u16x8*>(&B1b[rr*128 + ((2*k8) ^ ((rr & 7) << 4))]) = v;
    }

    float b1c[8], b2c[8];
    #pragma unroll
    for (int cb = 0; cb < 8; ++cb) { b1c[cb] = m1b[cb*16 + l15]; b2c[cb] = m2b[cb*16 + l15]; }

    const float step = 10.0f / 49.0f;
    const float coeff = -0.5f / (step * step);

    for (int mt = blockIdx.x; mt < mtiles; mt += gridDim.x) {
        __syncthreads();   // prev tile's reads of A1/U done; 1st iter: B1 staged

        // ---- stage A1: generate Gaussian smearing rows ----
        #pragma unroll
        for (int p = 0; p < 4; ++p) {
            int rr = p * 32 + (tid >> 3);
            int k8 = (tid & 7) * 8;
            float w = ew_s[mt*128 + rr];
            u16x8 v;
            #pragma unroll
            for (int j = 0; j < 8; ++j) {
                int k = k8 + j;
                float d = w - (float)k * step;
                float g = (k < NGAUSS) ? __expf(coeff * d * d) : 0.0f;
                v[j] = f2bf(g);
            }
            *reinterpret_cast<u16x8*>(&A1b[rr*128 + ((2*k8) ^ ((rr & 7) << 4))]) = v;
        }
        __syncthreads();

        // ---- GEMM1: u = ssp(ea @ m1w + b1), K=64 ----
        f32x4 acc1[2][8];
        #pragma unroll
        for (int i = 0; i < 2; ++i)
            #pragma unroll
            for (int j = 0; j < 8; ++j) { acc1[i][j].x=0.f; acc1[i][j].y=0.f; acc1[i][j].z=0.f; acc1[i][j].w=0.f; }
        #pragma unroll
        for (int ks = 0; ks < 2; ++ks) {
            int k = ks*32 + kgrp;
            bf16x8 af[2];
            #pragma unroll
            for (int rt = 0; rt < 2; ++rt) {
                int r = rbase + rt*16 + l15;
                af[rt] = *reinterpret_cast<const bf16x8*>(&A1b[r*128 + ((2*k) ^ ((r & 7) << 4))]);
            }
            #pragma unroll
            for (int cb = 0; cb < 8; ++cb) {
                int c = cb*16 + l15;
                bf16x8 bv = *reinterpret_cast<const bf16x8*>(&B1b[c*128 + ((2*k) ^ ((c & 7) << 4))]);
                acc1[0][cb] = __builtin_amdgcn_mfma_f32_16x16x32_bf16(af[0], bv, acc1[0][cb], 0, 0, 0);
                acc1[1][cb] = __builtin_amdgcn_mfma_f32_16x16x32_bf16(af[1], bv, acc1[1][cb], 0, 0, 0);
            }
        }
        // epilogue1: ssp -> u (bf16) into LDS U, swizzled [edge][feat]
        #pragma unroll
        for (int rt = 0; rt < 2; ++rt) {
            #pragma unroll
            for (int cb = 0; cb < 8; ++cb) {
                int c = cb*16 + l15;
                #pragma unroll
                for (int i = 0; i < 4; ++i) {
                    int rrow = rbase + rt*16 + (lane >> 4)*4 + i;
                    ushort us = f2bf(ssp_f(acc1[rt][cb][i] + b1c[cb]));
                    *reinterpret_cast<ushort*>(&Ub[rrow*256 + ((2*c) ^ ((rrow & 7) << 4))]) = us;
                }
            }
        }
        __syncthreads();   // all A1 reads done (safe to overwrite), U visible

        // ---- GEMM2: Wf = u @ m2w + b2, K=128 (m2T staged into A1 space, 2 chunks) ----
        f32x4 acc2[2][8];
        #pragma unroll
        for (int i = 0; i < 2; ++i)
            #pragma unroll
            for (int j = 0; j < 8; ++j) { acc2[i][j].x=0.f; acc2[i][j].y=0.f; acc2[i][j].z=0.f; acc2[i][j].w=0.f; }
        #pragma unroll
        for (int kh = 0; kh < 2; ++kh) {
            if (kh) __syncthreads();   // chunk-0 B reads complete
            #pragma unroll
            for (int p = 0; p < 4; ++p) {
                int rr = p * 32 + (tid >> 3);
                int kk = (tid & 7) * 8;
                u16x8 v = *reinterpret_cast<const u16x8*>(&m2T[(size_t)rr*128 + kh*64 + kk]);
                *reinterpret_cast<u16x8*>(&A1b[rr*128 + ((2*kk) ^ ((rr & 7) << 4))]) = v;
            }
            __syncthreads();
            #pragma unroll
            for (int ks2 = 0; ks2 < 2; ++ks2) {
                int ku = kh*64 + ks2*32 + kgrp;
                int kb = ks2*32 + kgrp;
                bf16x8 af[2];
                #pragma unroll
                for (int rt = 0; rt < 2; ++rt) {
                    int r = rbase + rt*16 + l15;
                    af[rt] = *reinterpret_cast<const bf16x8*>(&Ub[r*256 + ((2*ku) ^ ((r & 7) << 4))]);
                }
                #pragma unroll
                for (int cb = 0; cb < 8; ++cb) {
                    int c = cb*16 + l15;
                    bf16x8 bv = *reinterpret_cast<const bf16x8*>(&A1b[c*128 + ((2*kb) ^ ((c & 7) << 4))]);
                    acc2[0][cb] = __builtin_amdgcn_mfma_f32_16x16x32_bf16(af[0], bv, acc2[0][cb], 0, 0, 0);
                    acc2[1][cb] = __builtin_amdgcn_mfma_f32_16x16x32_bf16(af[1], bv, acc2[1][cb], 0, 0, 0);
                }
            }
        }

        // ---- epilogue2: fold cenv, store Wf bf16 ----
        #pragma unroll
        for (int rt = 0; rt < 2; ++rt) {
            float cv[4];
            #pragma unroll
            for (int i = 0; i < 4; ++i)
                cv[i] = cenv_s[mt*128 + rbase + rt*16 + (lane >> 4)*4 + i];
            #pragma unroll
            for (int cb = 0; cb < 8; ++cb) {
                int c = cb*16 + l15;
                #pragma unroll
                for (int i = 0; i < 4; ++i) {
                    int slot = mt*128 + rbase + rt*16 + (lane >> 4)*4 + i;
                    Wf[(size_t)slot * HD + c] = f2bf((acc2[rt][cb][i] + b2c[cb]) * cv[i]);
                }
            }
        }
    }
}

// ================= unified MFMA GEMM (node-side) =================
// ASRC: 0 = f32 rows, 1 = bf16 rows
// EPI:  0 = f32 store; 1 = bias+ssp->bf16; 3 = bias+residual f32; 4 = bias+relu f32
template<int K, int ASRC, int EPI, bool BSPLIT>
__global__ __launch_bounds__(256, 2) void gemm_kernel(
        const void* __restrict__ AsrcV, const ushort* __restrict__ BThi,
        const ushort* __restrict__ BTlo, const float* __restrict__ bias,
        float* __restrict__ fdst, ushort* __restrict__ bdst, int mtiles) {
    constexpr int BKW = BSPLIT ? 64 : K;
    __shared__ ushort A_lds[128 * K];
    __shared__ ushort B_lds[128 * BKW];
    char* Ab = (char*)A_lds;
    char* Bb = (char*)B_lds;
    const int tid  = threadIdx.x;
    const int lane = tid & 63;
    const int wave = tid >> 6;
    const int l15  = lane & 15;
    const int kgrp = (lane >> 4) * 8;

    if (!BSPLIT) {
        constexpr int PASSES = 128 * K / (256 * 8);
        #pragma unroll
        for (int p = 0; p < PASSES; ++p) {
            int rr, k8;
            if (K == 128) { rr = p * 16 + (tid >> 4); k8 = (tid & 15) * 8; }
            else          { rr = p * 32 + (tid >> 3); k8 = (tid & 7) * 8; }
            u16x8 v = *reinterpret_cast<const u16x8*>(&BThi[(size_t)rr * K + k8]);
            *reinterpret_cast<u16x8*>(&Bb[rr*(2*K) + ((2*k8) ^ ((rr & 7) << 4))]) = v;
        }
        __syncthreads();
    }

    for (int mt = blockIdx.x; mt < mtiles; mt += gridDim.x) {
        __syncthreads();
        if (ASRC == 0) {
            const float* A = (const float*)AsrcV;
            #pragma unroll
            for (int p = 0; p < 16; ++p) {
                int rr = p * 8 + (tid >> 5);
                int k4 = (tid & 31) * 4;
                f32x4 v = *reinterpret_cast<const f32x4*>(&A[(size_t)(mt*128 + rr)*K + k4]);
                u16x4 b;
                b.x = f2bf(v.x); b.y = f2bf(v.y); b.z = f2bf(v.z); b.w = f2bf(v.w);
                *reinterpret_cast<u16x4*>(&Ab[rr*(2*K) + ((2*k4) ^ ((rr & 7) << 4))]) = b;
            }
        } else {
            const ushort* A = (const ushort*)AsrcV;
            #pragma unroll
            for (int p = 0; p < (K == 128 ? 8 : 4); ++p) {
                int rr, k8;
                if (K == 128) { rr = p * 16 + (tid >> 4); k8 = (tid & 15) * 8; }
                else          { rr = p * 32 + (tid >> 3); k8 = (tid & 7) * 8; }
                u16x8 v = *reinterpret_cast<const u16x8*>(&A[(size_t)(mt*128 + rr)*K + k8]);
                *reinterpret_cast<u16x8*>(&Ab[rr*(2*K) + ((2*k8) ^ ((rr & 7) << 4))]) = v;
            }
        }

        f32x4 acc[2][8];
        #pragma unroll
        for (int i = 0; i < 2; ++i)
            #pragma unroll
            for (int j = 0; j < 8; ++j) { acc[i][j].x=0.f; acc[i][j].y=0.f; acc[i][j].z=0.f; acc[i][j].w=0.f; }

        const int rbase = wave * 32;

        if (!BSPLIT) {
            __syncthreads();
            #pragma unroll
            for (int ks = 0; ks < K/32; ++ks) {
                int k = ks*32 + kgrp;
                bf16x8 af[2];
                #pragma unroll
                for (int rt = 0; rt < 2; ++rt) {
                    int r = rbase + rt*16 + l15;
                    af[rt] = *reinterpret_cast<const bf16x8*>(&Ab[r*(2*K) + ((2*k) ^ ((r & 7) << 4))]);
                }
                #pragma unroll
                for (int cb = 0; cb < 8; ++cb) {
                    int c = cb*16 + l15;
                    bf16x8 bv = *reinterpret_cast<const bf16x8*>(&Bb[c*(2*K) + ((2*k) ^ ((c & 7) << 4))]);
                    acc[0][cb] = __builtin_amdgcn_mfma_f32_16x16x32_bf16(af[0], bv, acc[0][cb], 0, 0, 0);
                    acc[1][cb] = __builtin_amdgcn_mfma_f32_16x16x32_bf16(af[1], bv, acc[1][cb], 0, 0, 0);
                }
            }
        } else {
            #pragma unroll
            for (int part = 0; part < 2; ++part) {
                const ushort* BT = part ? BTlo : BThi;
                #pragma unroll
                for (int kh = 0; kh < K/64; ++kh) {
                    __syncthreads();
                    #pragma unroll
                    for (int p = 0; p < 4; ++p) {
                        int rr = p * 32 + (tid >> 3);
                        int kk = (tid & 7) * 8;
                        u16x8 v = *reinterpret_cast<const u16x8*>(&BT[(size_t)rr*K + kh*64 + kk]);
                        *reinterpret_cast<u16x8*>(&Bb[rr*128 + ((2*kk) ^ ((rr & 7) << 4))]) = v;
                    }
                    __syncthreads();
                    #pragma unroll
                    for (int ks2 = 0; ks2 < 2; ++ks2) {
                        int ka = kh*64 + ks2*32 + kgrp;
                        int kb = ks2*32 + kgrp;
                        bf16x8 af[2];
                        #pragma unroll
                        for (int rt = 0; rt < 2; ++rt) {
                            int r = rbase + rt*16 + l15;
                            af[rt] = *reinterpret_cast<const bf16x8*>(&Ab[r*(2*K) + ((2*ka) ^ ((r & 7) << 4))]);
                        }
                        #pragma unroll
                        for (int cb = 0; cb < 8; ++cb) {
                            int c = cb*16 + l15;
                            bf16x8 bv = *reinterpret_cast<const bf16x8*>(&Bb[c*128 + ((2*kb) ^ ((c & 7) << 4))]);
                            acc[0][cb] = __builtin_amdgcn_mfma_f32_16x16x32_bf16(af[0], bv, acc[0][cb], 0, 0, 0);
                            acc[1][cb] = __builtin_amdgcn_mfma_f32_16x16x32_bf16(af[1], bv, acc[1][cb], 0, 0, 0);
                        }
                    }
                }
            }
        }

        float bcol[8];
        if (EPI != 0) {
            #pragma unroll
            for (int cb = 0; cb < 8; ++cb) bcol[cb] = bias[cb*16 + l15];
        }
        #pragma unroll
        for (int rt = 0; rt < 2; ++rt) {
            #pragma unroll
            for (int cb = 0; cb < 8; ++cb) {
                #pragma unroll
                for (int i = 0; i < 4; ++i) {
                    int row = mt*128 + rbase + rt*16 + (lane >> 4)*4 + i;
                    int col = cb*16 + l15;
                    size_t off = (size_t)row * HD + col;
                    float v = acc[rt][cb][i];
                    if (EPI == 0)      fdst[off] = v;
                    else if (EPI == 1) bdst[off] = f2bf(ssp_f(v + bcol[cb]));
                    else if (EPI == 3) fdst[off] = fdst[off] + v + bcol[cb];
                    else               fdst[off] = fmaxf(v + bcol[cb], 0.0f);
                }
            }
        }
    }
}

// ================= streaming segment-sum (dest-sorted, no atomics) =================
__global__ void segsum_kernel(const ushort* __restrict__ Wf, const int* __restrict__ rowp,
                              const int* __restrict__ row_s,
                              const float* __restrict__ hx, float* __restrict__ agg, int N) {
    const int n = blockIdx.x;
    if (n >= N) return;
    const int t = threadIdx.x;
    const int s0 = rowp[n], s1 = rowp[n + 1];
    float acc = 0.0f;
    int s = s0;
    for (; s + 2 <= s1; s += 2) {
        float w0 = bf2f(Wf[(size_t)s * HD + t]);
        float w1 = bf2f(Wf[(size_t)(s+1) * HD + t]);
        float h0 = hx[(size_t)row_s[s] * HD + t];
        float h1 = hx[(size_t)row_s[s+1] * HD + t];
        acc += w0 * h0;
        acc += w1 * h1;
    }
    if (s < s1)
        acc += bf2f(Wf[(size_t)s * HD + t]) * hx[(size_t)row_s[s] * HD + t];
    agg[(size_t)n * HD + t] = acc;
}

// ================= mean pool =================
__global__ void pool_kernel(const float* __restrict__ h1, const int* __restrict__ batch,
                            float* __restrict__ gsum, float* __restrict__ gcnt, int N) {
    __shared__ float pool[NGRAPH][HD];
    __shared__ float cnt[NGRAPH];
    const int t = threadIdx.x;
    #pragma unroll
    for (int g = 0; g < NGRAPH; ++g) pool[g][t] = 0.0f;
    if (t < NGRAPH) cnt[t] = 0.0f;
    __syncthreads();
    int chunk = (N + gridDim.x - 1) / gridDim.x;
    int n0 = blockIdx.x * chunk, n1 = min(N, n0 + chunk);
    for (int n = n0; n < n1; ++n) {
        int b = batch[n];
        pool[b][t] += h1[(size_t)n * HD + t];
        if (t == 0) cnt[b] += 1.0f;
    }
    __syncthreads();
    #pragma unroll
    for (int g = 0; g < NGRAPH; ++g) atomicAdd(&gsum[g*HD + t], pool[g][t]);
    if (t < NGRAPH) atomicAdd(&gcnt[t], cnt[t]);
}

// ================= head =================
__global__ void finalize_kernel(const float* __restrict__ gsum, const float* __restrict__ gcnt,
                                const float* __restrict__ l1w, const float* __restrict__ l1b,
                                const float* __restrict__ l2w, const float* __restrict__ l2b,
                                float* __restrict__ d_out) {
    __shared__ float ge[HD];
    __shared__ float h2[HD];
    const int g = blockIdx.x, t = threadIdx.x;
    float cnt = fmaxf(gcnt[g], 1.0f);
    float v = gsum[g*HD + t] / cnt;
    d_out[g*HD + t] = v;
    ge[t] = v;
    __syncthreads();
    float acc = l1b[t];
    #pragma unroll 8
    for (int k = 0; k < HD; ++k) acc += ge[k] * l1w[k*HD + t];
    h2[t] = fmaxf(acc, 0.0f);
    __syncthreads();
    if (t < NCLS) {
        float o = l2b[t];
        #pragma unroll 8
        for (int k = 0; k < HD; ++k) o += h2[k] * l2w[k*NCLS + t];
        d_out[NGRAPH*HD + g*NCLS + t] = o;
    }
}

extern "C" void kernel_launch(void* const* d_in, const int* in_sizes, int n_in,
                              void* d_out, int out_size, void* d_ws, size_t ws_size,
                              hipStream_t stream) {
    const float* x     = (const float*)d_in[0];
    const float* pos   = (const float*)d_in[1];
    const int*   eidx  = (const int*)d_in[2];
    const int*   batch = (const int*)d_in[3];
    const float* emb_w = (const float*)d_in[4];
    const float* emb_b = (const float*)d_in[5];
    const float* m1w   = (const float*)d_in[6];
    const float* m1b   = (const float*)d_in[7];
    const float* m2w   = (const float*)d_in[8];
    const float* m2b   = (const float*)d_in[9];
    const float* c1w   = (const float*)d_in[10];
    const float* c2w   = (const float*)d_in[11];
    const float* c2b   = (const float*)d_in[12];
    const float* lw    = (const float*)d_in[13];
    const float* lb    = (const float*)d_in[14];
    const float* l1w   = (const float*)d_in[15];
    const float* l1b   = (const float*)d_in[16];
    const float* l2w   = (const float*)d_in[17];
    const float* l2b   = (const float*)d_in[18];

    const int N = in_sizes[0] / 21;          // 20000
    const int E = in_sizes[2] / 2;           // 640000
    const int* row = eidx;
    const int* col = eidx + E;
    const int NT   = (N + 127) / 128;        // 157
    const int Npad = NT * 128;
    const int ET   = E / 128;                // 5000

    size_t off = 0;
    char* base = (char*)d_ws;
    auto alloc = [&](size_t bytes) -> void* {
        off = (off + 255) & ~(size_t)255;
        void* p = base + off;
        off += bytes;
        return p;
    };
    int*    deg     = (int*)alloc((size_t)N * 4);
    int*    cursor  = (int*)alloc((size_t)N * 4);
    int*    rowp    = (int*)alloc((size_t)(N + 1) * 4);
    int*    row_s   = (int*)alloc((size_t)E * 4);
    float*  ew_s    = (float*)alloc((size_t)E * 4);
    float*  cenv_s  = (float*)alloc((size_t)E * 4);
    float*  h       = (float*)alloc((size_t)Npad * HD * 4);
    float*  hx      = (float*)alloc((size_t)Npad * HD * 4);
    float*  agg     = (float*)alloc((size_t)Npad * HD * 4);
    float*  h1      = (float*)alloc((size_t)Npad * HD * 4);
    ushort* tmpb    = (ushort*)alloc((size_t)Npad * HD * 2);
    ushort* Wf      = (ushort*)alloc((size_t)E * HD * 2);
    ushort* m1T     = (ushort*)alloc((size_t)6 * 128 * 64 * 2);
    ushort* nodeThi = (ushort*)alloc((size_t)19 * 128 * 128 * 2);
    ushort* nodeTlo = (ushort*)alloc((size_t)19 * 128 * 128 * 2);
    ushort* m2T     = (ushort*)alloc((size_t)6 * 128 * 128 * 2);
    float*  gsum    = (float*)alloc((size_t)NGRAPH * HD * 4);
    float*  gcnt    = (float*)alloc((size_t)NGRAPH * 4);

    // ---- one-time: weight prep + CSR ----
    prep_kernel<<<1792, 256, 0, stream>>>(m1w, c1w, c2w, lw, l1w, m2w,
                                          m1T, nodeThi, nodeTlo, m2T);
    hipMemsetAsync(deg, 0, (size_t)N * 4, stream);
    hist_kernel<<<(E + 255)/256, 256, 0, stream>>>(col, deg, E);
    scan_kernel<<<1, 256, 0, stream>>>(deg, rowp, cursor, N);
    fill_kernel<<<(E + 255)/256, 256, 0, stream>>>(row, col, pos, cursor,
                                                   row_s, ew_s, cenv_s, E);
    embed_kernel<<<(N*HD + 255)/256, 256, 0, stream>>>(x, emb_w, emb_b, h, N);

    for (int l = 0; l < NLAYER; ++l) {
        const ushort* c1Thi = nodeThi + (size_t)l * 16384;
        const ushort* c1Tlo = nodeTlo + (size_t)l * 16384;
        const ushort* c2Thi = nodeThi + (size_t)(6 + l) * 16384;
        const ushort* c2Tlo = nodeTlo + (size_t)(6 + l) * 16384;
        const ushort* lThi  = nodeThi + (size_t)(12 + l) * 16384;
        const ushort* lTlo  = nodeTlo + (size_t)(12 + l) * 16384;

        // hx = h @ c1w
        gemm_kernel<128, 0, 0, true><<<NT, 256, 0, stream>>>(
            h, c1Thi, c1Tlo, nullptr, hx, nullptr, NT);
        // Wf = (ssp(ea@m1w+b1)@m2w + b2)*cenv   (fully fused, u in LDS)
        efilter_kernel<<<2500, 256, 0, stream>>>(
            ew_s, m1T + (size_t)l * 8192, m2T + (size_t)l * 16384,
            m1b + l*HD, m2b + l*HD, cenv_s, Wf, ET);
        // agg[n] = sum_s Wf[s]*hx[row_s[s]]
        segsum_kernel<<<N, HD, 0, stream>>>(Wf, rowp, row_s, hx, agg, N);
        // tmpb = bf16(ssp(agg @ c2w + c2b))
        gemm_kernel<128, 0, 1, true><<<NT, 256, 0, stream>>>(
            agg, c2Thi, c2Tlo, c2b + l*HD, nullptr, tmpb, NT);
        // h += tmpb @ lw + lb
        gemm_kernel<128, 1, 3, true><<<NT, 256, 0, stream>>>(
            tmpb, lThi, lTlo, lb + l*HD, h, nullptr, NT);
    }

    gemm_kernel<128, 0, 4, true><<<NT, 256, 0, stream>>>(
        h, nodeThi + (size_t)18 * 16384, nodeTlo + (size_t)18 * 16384,
        l1b, h1, nullptr, NT);

    hipMemsetAsync(gsum, 0, (size_t)(NGRAPH*HD + NGRAPH) * 4, stream);
    pool_kernel<<<256, HD, 0, stream>>>(h1, batch, gsum, gcnt, N);
    finalize_kernel<<<NGRAPH, HD, 0, stream>>>(gsum, gcnt, l1w, l1b, l2w, l2b,
                                               (float*)d_out);
}

// Round 6
// 766.070 us; speedup vs baseline: 89.1083x; 1.7757x over previous
//
#include <hip/hip_runtime.h>
#include <hip/hip_bf16.h>

#define HD 128
#define NGAUSS 50
#define NLAYER 6
#define NGRAPH 16
#define NCLS 97
#define NTAB 2048
#define WMAX 12.0f

typedef __attribute__((ext_vector_type(8))) short bf16x8;
typedef __attribute__((ext_vector_type(4))) float f32x4;
typedef __attribute__((ext_vector_type(8))) ushort u16x8;
typedef __attribute__((ext_vector_type(4))) ushort u16x4;

// fast shifted-softplus: softplus(x)-ln2 = max(x,0) + ln(0.5 + 0.5*exp(-|x|))
__device__ __forceinline__ float ssp_f(float x) {
    float e = __expf(-fabsf(x));
    return fmaxf(x, 0.0f) + __logf(0.5f + 0.5f * e);
}
__device__ __forceinline__ ushort f2bf(float f) {   // RNE f32->bf16
    uint u = __float_as_uint(f);
    return (ushort)((u + 0x7FFFu + ((u >> 16) & 1u)) >> 16);
}
__device__ __forceinline__ float bf2f(ushort s) {
    return __uint_as_float(((uint)s) << 16);
}

// ================= CSR build =================
__global__ void hist_kernel(const int* __restrict__ col, int* __restrict__ deg, int E) {
    int e = blockIdx.x * blockDim.x + threadIdx.x;
    if (e < E) atomicAdd(&deg[col[e]], 1);
}

__global__ void scan_kernel(const int* __restrict__ deg, int* __restrict__ rowp,
                            int* __restrict__ cursor, int N) {
    __shared__ int part[256];
    const int t = threadIdx.x;
    const int chunk = (N + 255) / 256;
    const int i0 = t * chunk, i1 = min(N, i0 + chunk);
    int s = 0;
    for (int i = i0; i < i1; ++i) s += deg[i];
    part[t] = s;
    __syncthreads();
    for (int off = 1; off < 256; off <<= 1) {
        int v = part[t];
        int add = (t >= off) ? part[t - off] : 0;
        __syncthreads();
        part[t] = v + add;
        __syncthreads();
    }
    int run = (t == 0) ? 0 : part[t - 1];
    for (int i = i0; i < i1; ++i) {
        rowp[i] = run; cursor[i] = run; run += deg[i];
    }
    if (t == 255) rowp[N] = run;
}

// per-slot metadata: {src row, table idx, (1-f)*cenv bits, f*cenv bits}
__global__ void fill_kernel(const int* __restrict__ row, const int* __restrict__ col,
                            const float* __restrict__ pos, int* __restrict__ cursor,
                            int4* __restrict__ meta, int E) {
    int e = blockIdx.x * blockDim.x + threadIdx.x;
    if (e >= E) return;
    int c = col[e], r = row[e];
    int slot = atomicAdd(&cursor[c], 1);
    float dx = pos[r*3+0] - pos[c*3+0];
    float dy = pos[r*3+1] - pos[c*3+1];
    float dz = pos[r*3+2] - pos[c*3+2];
    float w = sqrtf(dx*dx + dy*dy + dz*dz);
    float cenv = 0.5f * (cosf(w * 0.31415926535897931f) + 1.0f);
    const float invDW = (float)(NTAB - 1) / WMAX;
    float tt = w * invDW;
    int i = min((int)tt, NTAB - 1);
    float f = fminf(tt - (float)i, 1.0f);
    meta[slot] = make_int4(r, i, __float_as_int((1.0f - f) * cenv),
                           __float_as_int(f * cenv));
}

// ================= weight prep: transpose + bf16 (hi/lo split for node mats) ========
__global__ void prep_kernel(const float* __restrict__ m1w, const float* __restrict__ c1w,
                            const float* __restrict__ c2w, const float* __restrict__ lw,
                            const float* __restrict__ l1w, const float* __restrict__ m2w,
                            ushort* __restrict__ m1T, ushort* __restrict__ nodeThi,
                            ushort* __restrict__ nodeTlo, ushort* __restrict__ m2T) {
    int idx = blockIdx.x * blockDim.x + threadIdx.x;
    const int S1 = 6*128*64, S2 = 19*128*128, S3 = 6*128*128;
    if (idx < S1) {
        int l = idx / 8192, r = idx % 8192, c = r / 64, k = r % 64;
        float v = (k < NGAUSS) ? m1w[(size_t)l*NGAUSS*128 + k*128 + c] : 0.0f;
        m1T[(size_t)l*8192 + c*64 + k] = f2bf(v);
    } else if (idx < S1 + S2) {
        int j = idx - S1;
        int m = j / 16384, r = j % 16384, c = r / 128, k = r % 128;
        const float* src;
        if (m < 6)       src = c1w + (size_t)m*16384;
        else if (m < 12) src = c2w + (size_t)(m-6)*16384;
        else if (m < 18) src = lw  + (size_t)(m-12)*16384;
        else             src = l1w;
        float v = src[k*128 + c];
        ushort hi = f2bf(v);
        nodeThi[(size_t)m*16384 + c*128 + k] = hi;
        nodeTlo[(size_t)m*16384 + c*128 + k] = f2bf(v - bf2f(hi));
    } else if (idx < S1 + S2 + S3) {
        int j = idx - S1 - S2;
        int l = j / 16384, r = j % 16384, c = r / 128, k = r % 128;
        m2T[(size_t)l*16384 + c*128 + k] = f2bf(m2w[(size_t)l*16384 + k*128 + c]);
    }
}

// ================= embedding =================
__global__ void embed_kernel(const float* __restrict__ x,
                             const float* __restrict__ emb_w, const float* __restrict__ emb_b,
                             float* __restrict__ h, int N) {
    int idx = blockIdx.x * blockDim.x + threadIdx.x;
    if (idx >= N * HD) return;
    int n = idx >> 7, t = idx & 127;
    float acc = emb_b[t];
    #pragma unroll
    for (int a = 0; a < 21; ++a) acc += x[n*21 + a] * emb_w[a*HD + t];
    h[idx] = acc;
}

// ================= filter table build: T6[l][j][:] = g_l(w_j), w_j = j*DW =========
// Exactly the proven efilter structure, run on the 2048-point grid (16 tiles/layer).
__global__ __launch_bounds__(256, 2) void buildtab_kernel(
        const ushort* __restrict__ m1T_all, const ushort* __restrict__ m2T_all,
        const float* __restrict__ m1b_all, const float* __restrict__ m2b_all,
        float* __restrict__ T6) {
    __shared__ ushort A1[128 * 64];   // gaussian tile, then m2T chunk
    __shared__ ushort B1[128 * 64];   // m1T resident
    __shared__ ushort U [128 * 128];  // intermediate u (bf16)
    char* A1b = (char*)A1;
    char* B1b = (char*)B1;
    char* Ub  = (char*)U;
    const int tid  = threadIdx.x;
    const int lane = tid & 63;
    const int wave = tid >> 6;
    const int l15  = lane & 15;
    const int kgrp = (lane >> 4) * 8;
    const int rbase = wave * 32;
    const int layer = blockIdx.x >> 4;
    const int mt    = blockIdx.x & 15;
    const ushort* m1T = m1T_all + (size_t)layer * 8192;
    const ushort* m2T = m2T_all + (size_t)layer * 16384;
    const float*  m1b = m1b_all + layer * HD;
    const float*  m2b = m2b_all + layer * HD;

    // stage m1T resident ([col][k64], swizzled)
    #pragma unroll
    for (int p = 0; p < 4; ++p) {
        int rr = p * 32 + (tid >> 3);
        int k8 = (tid & 7) * 8;
        u16x8 v = *reinterpret_cast<const u16x8*>(&m1T[(size_t)rr * 64 + k8]);
        *reinterpret_cast<u16x8*>(&B1b[rr*128 + ((2*k8) ^ ((rr & 7) << 4))]) = v;
    }

    float b1c[8], b2c[8];
    #pragma unroll
    for (int cb = 0; cb < 8; ++cb) { b1c[cb] = m1b[cb*16 + l15]; b2c[cb] = m2b[cb*16 + l15]; }

    const float step = 10.0f / 49.0f;
    const float coeff = -0.5f / (step * step);
    const float DW = WMAX / (float)(NTAB - 1);

    // ---- stage A1: gaussian rows for grid points ----
    #pragma unroll
    for (int p = 0; p < 4; ++p) {
        int rr = p * 32 + (tid >> 3);
        int k8 = (tid & 7) * 8;
        float w = (float)(mt*128 + rr) * DW;
        u16x8 v;
        #pragma unroll
        for (int j = 0; j < 8; ++j) {
            int k = k8 + j;
            float d = w - (float)k * step;
            float g = (k < NGAUSS) ? __expf(coeff * d * d) : 0.0f;
            v[j] = f2bf(g);
        }
        *reinterpret_cast<u16x8*>(&A1b[rr*128 + ((2*k8) ^ ((rr & 7) << 4))]) = v;
    }
    __syncthreads();

    // ---- GEMM1: u = ssp(ea @ m1w + b1), K=64 ----
    f32x4 acc1[2][8];
    #pragma unroll
    for (int i = 0; i < 2; ++i)
        #pragma unroll
        for (int j = 0; j < 8; ++j) { acc1[i][j].x=0.f; acc1[i][j].y=0.f; acc1[i][j].z=0.f; acc1[i][j].w=0.f; }
    #pragma unroll
    for (int ks = 0; ks < 2; ++ks) {
        int k = ks*32 + kgrp;
        bf16x8 af[2];
        #pragma unroll
        for (int rt = 0; rt < 2; ++rt) {
            int r = rbase + rt*16 + l15;
            af[rt] = *reinterpret_cast<const bf16x8*>(&A1b[r*128 + ((2*k) ^ ((r & 7) << 4))]);
        }
        #pragma unroll
        for (int cb = 0; cb < 8; ++cb) {
            int c = cb*16 + l15;
            bf16x8 bv = *reinterpret_cast<const bf16x8*>(&B1b[c*128 + ((2*k) ^ ((c & 7) << 4))]);
            acc1[0][cb] = __builtin_amdgcn_mfma_f32_16x16x32_bf16(af[0], bv, acc1[0][cb], 0, 0, 0);
            acc1[1][cb] = __builtin_amdgcn_mfma_f32_16x16x32_bf16(af[1], bv, acc1[1][cb], 0, 0, 0);
        }
    }
    // epilogue1: ssp -> U (bf16, swizzled [row][feat])
    #pragma unroll
    for (int rt = 0; rt < 2; ++rt) {
        #pragma unroll
        for (int cb = 0; cb < 8; ++cb) {
            int c = cb*16 + l15;
            #pragma unroll
            for (int i = 0; i < 4; ++i) {
                int rrow = rbase + rt*16 + (lane >> 4)*4 + i;
                ushort us = f2bf(ssp_f(acc1[rt][cb][i] + b1c[cb]));
                *reinterpret_cast<ushort*>(&Ub[rrow*256 + ((2*c) ^ ((rrow & 7) << 4))]) = us;
            }
        }
    }
    __syncthreads();   // A1 reads done, U visible

    // ---- GEMM2: T = u @ m2w + b2, K=128 (m2T staged into A1, 2 chunks) ----
    f32x4 acc2[2][8];
    #pragma unroll
    for (int i = 0; i < 2; ++i)
        #pragma unroll
        for (int j = 0; j < 8; ++j) { acc2[i][j].x=0.f; acc2[i][j].y=0.f; acc2[i][j].z=0.f; acc2[i][j].w=0.f; }
    #pragma unroll
    for (int kh = 0; kh < 2; ++kh) {
        if (kh) __syncthreads();
        #pragma unroll
        for (int p = 0; p < 4; ++p) {
            int rr = p * 32 + (tid >> 3);
            int kk = (tid & 7) * 8;
            u16x8 v = *reinterpret_cast<const u16x8*>(&m2T[(size_t)rr*128 + kh*64 + kk]);
            *reinterpret_cast<u16x8*>(&A1b[rr*128 + ((2*kk) ^ ((rr & 7) << 4))]) = v;
        }
        __syncthreads();
        #pragma unroll
        for (int ks2 = 0; ks2 < 2; ++ks2) {
            int ku = kh*64 + ks2*32 + kgrp;
            int kb = ks2*32 + kgrp;
            bf16x8 af[2];
            #pragma unroll
            for (int rt = 0; rt < 2; ++rt) {
                int r = rbase + rt*16 + l15;
                af[rt] = *reinterpret_cast<const bf16x8*>(&Ub[r*256 + ((2*ku) ^ ((r & 7) << 4))]);
            }
            #pragma unroll
            for (int cb = 0; cb < 8; ++cb) {
                int c = cb*16 + l15;
                bf16x8 bv = *reinterpret_cast<const bf16x8*>(&A1b[c*128 + ((2*kb) ^ ((c & 7) << 4))]);
                acc2[0][cb] = __builtin_amdgcn_mfma_f32_16x16x32_bf16(af[0], bv, acc2[0][cb], 0, 0, 0);
                acc2[1][cb] = __builtin_amdgcn_mfma_f32_16x16x32_bf16(af[1], bv, acc2[1][cb], 0, 0, 0);
            }
        }
    }

    // store T6 (f32)
    #pragma unroll
    for (int rt = 0; rt < 2; ++rt) {
        #pragma unroll
        for (int cb = 0; cb < 8; ++cb) {
            int c = cb*16 + l15;
            #pragma unroll
            for (int i = 0; i < 4; ++i) {
                int rrow = rbase + rt*16 + (lane >> 4)*4 + i;
                T6[((size_t)layer*NTAB + mt*128 + rrow) * HD + c] = acc2[rt][cb][i] + b2c[cb];
            }
        }
    }
}

// pack table rows i and i+1 as {bf16,bf16} in one u32 (single-load lerp endpoints)
__global__ void packtab_kernel(const float* __restrict__ T6, uint* __restrict__ P6) {
    int idx = blockIdx.x * blockDim.x + threadIdx.x;
    if (idx >= 6 * NTAB * HD) return;
    int r = (idx >> 7) & (NTAB - 1);
    float v0 = T6[idx];
    float v1 = (r + 1 < NTAB) ? T6[idx + HD] : v0;
    P6[idx] = ((uint)f2bf(v0)) | (((uint)f2bf(v1)) << 16);
}

// ================= unified MFMA GEMM (node-side) =================
// ASRC: 0 = f32 rows, 1 = bf16 rows
// EPI:  0 = f32 store; 1 = bias+ssp->bf16; 3 = bias+residual f32; 4 = bias+relu f32
template<int K, int ASRC, int EPI, bool BSPLIT>
__global__ __launch_bounds__(256, 2) void gemm_kernel(
        const void* __restrict__ AsrcV, const ushort* __restrict__ BThi,
        const ushort* __restrict__ BTlo, const float* __restrict__ bias,
        float* __restrict__ fdst, ushort* __restrict__ bdst, int mtiles) {
    constexpr int BKW = BSPLIT ? 64 : K;
    __shared__ ushort A_lds[128 * K];
    __shared__ ushort B_lds[128 * BKW];
    char* Ab = (char*)A_lds;
    char* Bb = (char*)B_lds;
    const int tid  = threadIdx.x;
    const int lane = tid & 63;
    const int wave = tid >> 6;
    const int l15  = lane & 15;
    const int kgrp = (lane >> 4) * 8;

    if (!BSPLIT) {
        constexpr int PASSES = 128 * K / (256 * 8);
        #pragma unroll
        for (int p = 0; p < PASSES; ++p) {
            int rr, k8;
            if (K == 128) { rr = p * 16 + (tid >> 4); k8 = (tid & 15) * 8; }
            else          { rr = p * 32 + (tid >> 3); k8 = (tid & 7) * 8; }
            u16x8 v = *reinterpret_cast<const u16x8*>(&BThi[(size_t)rr * K + k8]);
            *reinterpret_cast<u16x8*>(&Bb[rr*(2*K) + ((2*k8) ^ ((rr & 7) << 4))]) = v;
        }
        __syncthreads();
    }

    for (int mt = blockIdx.x; mt < mtiles; mt += gridDim.x) {
        __syncthreads();
        if (ASRC == 0) {
            const float* A = (const float*)AsrcV;
            #pragma unroll
            for (int p = 0; p < 16; ++p) {
                int rr = p * 8 + (tid >> 5);
                int k4 = (tid & 31) * 4;
                f32x4 v = *reinterpret_cast<const f32x4*>(&A[(size_t)(mt*128 + rr)*K + k4]);
                u16x4 b;
                b.x = f2bf(v.x); b.y = f2bf(v.y); b.z = f2bf(v.z); b.w = f2bf(v.w);
                *reinterpret_cast<u16x4*>(&Ab[rr*(2*K) + ((2*k4) ^ ((rr & 7) << 4))]) = b;
            }
        } else {
            const ushort* A = (const ushort*)AsrcV;
            #pragma unroll
            for (int p = 0; p < (K == 128 ? 8 : 4); ++p) {
                int rr, k8;
                if (K == 128) { rr = p * 16 + (tid >> 4); k8 = (tid & 15) * 8; }
                else          { rr = p * 32 + (tid >> 3); k8 = (tid & 7) * 8; }
                u16x8 v = *reinterpret_cast<const u16x8*>(&A[(size_t)(mt*128 + rr)*K + k8]);
                *reinterpret_cast<u16x8*>(&Ab[rr*(2*K) + ((2*k8) ^ ((rr & 7) << 4))]) = v;
            }
        }

        f32x4 acc[2][8];
        #pragma unroll
        for (int i = 0; i < 2; ++i)
            #pragma unroll
            for (int j = 0; j < 8; ++j) { acc[i][j].x=0.f; acc[i][j].y=0.f; acc[i][j].z=0.f; acc[i][j].w=0.f; }

        const int rbase = wave * 32;

        if (!BSPLIT) {
            __syncthreads();
            #pragma unroll
            for (int ks = 0; ks < K/32; ++ks) {
                int k = ks*32 + kgrp;
                bf16x8 af[2];
                #pragma unroll
                for (int rt = 0; rt < 2; ++rt) {
                    int r = rbase + rt*16 + l15;
                    af[rt] = *reinterpret_cast<const bf16x8*>(&Ab[r*(2*K) + ((2*k) ^ ((r & 7) << 4))]);
                }
                #pragma unroll
                for (int cb = 0; cb < 8; ++cb) {
                    int c = cb*16 + l15;
                    bf16x8 bv = *reinterpret_cast<const bf16x8*>(&Bb[c*(2*K) + ((2*k) ^ ((c & 7) << 4))]);
                    acc[0][cb] = __builtin_amdgcn_mfma_f32_16x16x32_bf16(af[0], bv, acc[0][cb], 0, 0, 0);
                    acc[1][cb] = __builtin_amdgcn_mfma_f32_16x16x32_bf16(af[1], bv, acc[1][cb], 0, 0, 0);
                }
            }
        } else {
            #pragma unroll
            for (int part = 0; part < 2; ++part) {
                const ushort* BT = part ? BTlo : BThi;
                #pragma unroll
                for (int kh = 0; kh < K/64; ++kh) {
                    __syncthreads();
                    #pragma unroll
                    for (int p = 0; p < 4; ++p) {
                        int rr = p * 32 + (tid >> 3);
                        int kk = (tid & 7) * 8;
                        u16x8 v = *reinterpret_cast<const u16x8*>(&BT[(size_t)rr*K + kh*64 + kk]);
                        *reinterpret_cast<u16x8*>(&Bb[rr*128 + ((2*kk) ^ ((rr & 7) << 4))]) = v;
                    }
                    __syncthreads();
                    #pragma unroll
                    for (int ks2 = 0; ks2 < 2; ++ks2) {
                        int ka = kh*64 + ks2*32 + kgrp;
                        int kb = ks2*32 + kgrp;
                        bf16x8 af[2];
                        #pragma unroll
                        for (int rt = 0; rt < 2; ++rt) {
                            int r = rbase + rt*16 + l15;
                            af[rt] = *reinterpret_cast<const bf16x8*>(&Ab[r*(2*K) + ((2*ka) ^ ((r & 7) << 4))]);
                        }
                        #pragma unroll
                        for (int cb = 0; cb < 8; ++cb) {
                            int c = cb*16 + l15;
                            bf16x8 bv = *reinterpret_cast<const bf16x8*>(&Bb[c*128 + ((2*kb) ^ ((c & 7) << 4))]);
                            acc[0][cb] = __builtin_amdgcn_mfma_f32_16x16x32_bf16(af[0], bv, acc[0][cb], 0, 0, 0);
                            acc[1][cb] = __builtin_amdgcn_mfma_f32_16x16x32_bf16(af[1], bv, acc[1][cb], 0, 0, 0);
                        }
                    }
                }
            }
        }

        float bcol[8];
        if (EPI != 0) {
            #pragma unroll
            for (int cb = 0; cb < 8; ++cb) bcol[cb] = bias[cb*16 + l15];
        }
        #pragma unroll
        for (int rt = 0; rt < 2; ++rt) {
            #pragma unroll
            for (int cb = 0; cb < 8; ++cb) {
                #pragma unroll
                for (int i = 0; i < 4; ++i) {
                    int row = mt*128 + wave*32 + rt*16 + (lane >> 4)*4 + i;
                    int col = cb*16 + l15;
                    size_t off = (size_t)row * HD + col;
                    float v = acc[rt][cb][i];
                    if (EPI == 0)      fdst[off] = v;
                    else if (EPI == 1) bdst[off] = f2bf(ssp_f(v + bcol[cb]));
                    else if (EPI == 3) fdst[off] = fdst[off] + v + bcol[cb];
                    else               fdst[off] = fmaxf(v + bcol[cb], 0.0f);
                }
            }
        }
    }
}

// ================= fused node block: h += (ssp(agg@c2+c2b))@lw + lb =================
// One 128-row tile per block. LDS: A1 32K + Bl 32K + U 32K = 96 KB (1 block/CU).
__global__ __launch_bounds__(256) void nodefused_kernel(
        const float* __restrict__ agg,
        const ushort* __restrict__ c2hi, const ushort* __restrict__ c2lo,
        const float* __restrict__ c2b,
        const ushort* __restrict__ lwhi, const ushort* __restrict__ lwlo,
        const float* __restrict__ lb,
        float* __restrict__ h, int mtiles) {
    __shared__ ushort A1[128 * 128];
    __shared__ ushort Bl[128 * 128];
    __shared__ ushort U [128 * 128];
    char* A1b = (char*)A1;
    char* Blb = (char*)Bl;
    char* Ub  = (char*)U;
    const int tid  = threadIdx.x;
    const int lane = tid & 63;
    const int wave = tid >> 6;
    const int l15  = lane & 15;
    const int kgrp = (lane >> 4) * 8;
    const int rbase = wave * 32;

    float b1c[8], b2c[8];
    #pragma unroll
    for (int cb = 0; cb < 8; ++cb) { b1c[cb] = c2b[cb*16 + l15]; b2c[cb] = lb[cb*16 + l15]; }

    for (int mt = blockIdx.x; mt < mtiles; mt += gridDim.x) {
        __syncthreads();
        // stage A1 = bf16(agg tile), swizzled
        #pragma unroll
        for (int p = 0; p < 16; ++p) {
            int rr = p * 8 + (tid >> 5);
            int k4 = (tid & 31) * 4;
            f32x4 v = *reinterpret_cast<const f32x4*>(&agg[(size_t)(mt*128 + rr)*HD + k4]);
            u16x4 b;
            b.x = f2bf(v.x); b.y = f2bf(v.y); b.z = f2bf(v.z); b.w = f2bf(v.w);
            *reinterpret_cast<u16x4*>(&A1b[rr*256 + ((2*k4) ^ ((rr & 7) << 4))]) = b;
        }

        // ---- GEMM1: acc = A1 @ (c2hi + c2lo) ----
        f32x4 acc[2][8];
        #pragma unroll
        for (int i = 0; i < 2; ++i)
            #pragma unroll
            for (int j = 0; j < 8; ++j) { acc[i][j].x=0.f; acc[i][j].y=0.f; acc[i][j].z=0.f; acc[i][j].w=0.f; }
        #pragma unroll
        for (int part = 0; part < 2; ++part) {
            const ushort* BT = part ? c2lo : c2hi;
            __syncthreads();   // part0: A1 visible; part1: prior Bl reads done
            #pragma unroll
            for (int p = 0; p < 8; ++p) {
                int rr = p * 16 + (tid >> 4);
                int k8 = (tid & 15) * 8;
                u16x8 v = *reinterpret_cast<const u16x8*>(&BT[(size_t)rr*128 + k8]);
                *reinterpret_cast<u16x8*>(&Blb[rr*256 + ((2*k8) ^ ((rr & 7) << 4))]) = v;
            }
            __syncthreads();
            #pragma unroll
            for (int ks = 0; ks < 4; ++ks) {
                int k = ks*32 + kgrp;
                bf16x8 af[2];
                #pragma unroll
                for (int rt = 0; rt < 2; ++rt) {
                    int r = rbase + rt*16 + l15;
                    af[rt] = *reinterpret_cast<const bf16x8*>(&A1b[r*256 + ((2*k) ^ ((r & 7) << 4))]);
                }
                #pragma unroll
                for (int cb = 0; cb < 8; ++cb) {
                    int c = cb*16 + l15;
                    bf16x8 bv = *reinterpret_cast<const bf16x8*>(&Blb[c*256 + ((2*k) ^ ((c & 7) << 4))]);
                    acc[0][cb] = __builtin_amdgcn_mfma_f32_16x16x32_bf16(af[0], bv, acc[0][cb], 0, 0, 0);
                    acc[1][cb] = __builtin_amdgcn_mfma_f32_16x16x32_bf16(af[1], bv, acc[1][cb], 0, 0, 0);
                }
            }
        }
        // epilogue1: ssp -> U (bf16, swizzled)
        #pragma unroll
        for (int rt = 0; rt < 2; ++rt) {
            #pragma unroll
            for (int cb = 0; cb < 8; ++cb) {
                int c = cb*16 + l15;
                #pragma unroll
                for (int i = 0; i < 4; ++i) {
                    int rrow = rbase + rt*16 + (lane >> 4)*4 + i;
                    ushort us = f2bf(ssp_f(acc[rt][cb][i] + b1c[cb]));
                    *reinterpret_cast<ushort*>(&Ub[rrow*256 + ((2*c) ^ ((rrow & 7) << 4))]) = us;
                }
            }
        }
        __syncthreads();   // U visible; all Bl/A1 reads done

        // ---- GEMM2: acc = U @ (lwhi + lwlo) ----
        #pragma unroll
        for (int i = 0; i < 2; ++i)
            #pragma unroll
            for (int j = 0; j < 8; ++j) { acc[i][j].x=0.f; acc[i][j].y=0.f; acc[i][j].z=0.f; acc[i][j].w=0.f; }
        #pragma unroll
        for (int part = 0; part < 2; ++part) {
            const ushort* BT = part ? lwlo : lwhi;
            if (part) __syncthreads();
            #pragma unroll
            for (int p = 0; p < 8; ++p) {
                int rr = p * 16 + (tid >> 4);
                int k8 = (tid & 15) * 8;
                u16x8 v = *reinterpret_cast<const u16x8*>(&BT[(size_t)rr*128 + k8]);
                *reinterpret_cast<u16x8*>(&Blb[rr*256 + ((2*k8) ^ ((rr & 7) << 4))]) = v;
            }
            __syncthreads();
            #pragma unroll
            for (int ks = 0; ks < 4; ++ks) {
                int k = ks*32 + kgrp;
                bf16x8 af[2];
                #pragma unroll
                for (int rt = 0; rt < 2; ++rt) {
                    int r = rbase + rt*16 + l15;
                    af[rt] = *reinterpret_cast<const bf16x8*>(&Ub[r*256 + ((2*k) ^ ((r & 7) << 4))]);
                }
                #pragma unroll
                for (int cb = 0; cb < 8; ++cb) {
                    int c = cb*16 + l15;
                    bf16x8 bv = *reinterpret_cast<const bf16x8*>(&Blb[c*256 + ((2*k) ^ ((c & 7) << 4))]);
                    acc[0][cb] = __builtin_amdgcn_mfma_f32_16x16x32_bf16(af[0], bv, acc[0][cb], 0, 0, 0);
                    acc[1][cb] = __builtin_amdgcn_mfma_f32_16x16x32_bf16(af[1], bv, acc[1][cb], 0, 0, 0);
                }
            }
        }
        // epilogue2: h += acc + lb
        #pragma unroll
        for (int rt = 0; rt < 2; ++rt) {
            #pragma unroll
            for (int cb = 0; cb < 8; ++cb) {
                #pragma unroll
                for (int i = 0; i < 4; ++i) {
                    int row = mt*128 + rbase + rt*16 + (lane >> 4)*4 + i;
                    int col = cb*16 + l15;
                    size_t off = (size_t)row * HD + col;
                    h[off] = h[off] + acc[rt][cb][i] + b2c[cb];
                }
            }
        }
    }
}

// ================= fused gather-lerp-segment-sum =================
// agg[n][t] = sum_slots (a*Tlo + b*Thi) * hx[row][t], endpoints packed in one u32.
__global__ __launch_bounds__(128) void gathersum_kernel(
        const uint* __restrict__ Tp, const int4* __restrict__ meta,
        const int* __restrict__ rowp, const float* __restrict__ hx,
        float* __restrict__ agg, int N) {
    const int n = blockIdx.x;
    if (n >= N) return;
    const int t = threadIdx.x;
    const int s0 = rowp[n], s1 = rowp[n + 1];
    float acc0 = 0.0f, acc1 = 0.0f;
    int s = s0;
    for (; s + 2 <= s1; s += 2) {
        int4 m0 = meta[s];
        int4 m1 = meta[s + 1];
        uint p0 = Tp[(size_t)m0.y * HD + t];
        float x0 = hx[(size_t)m0.x * HD + t];
        uint p1 = Tp[(size_t)m1.y * HD + t];
        float x1 = hx[(size_t)m1.x * HD + t];
        float w0 = __int_as_float(m0.z) * __uint_as_float(p0 << 16)
                 + __int_as_float(m0.w) * __uint_as_float(p0 & 0xFFFF0000u);
        float w1 = __int_as_float(m1.z) * __uint_as_float(p1 << 16)
                 + __int_as_float(m1.w) * __uint_as_float(p1 & 0xFFFF0000u);
        acc0 += w0 * x0;
        acc1 += w1 * x1;
    }
    if (s < s1) {
        int4 m0 = meta[s];
        uint p0 = Tp[(size_t)m0.y * HD + t];
        float x0 = hx[(size_t)m0.x * HD + t];
        acc0 += (__int_as_float(m0.z) * __uint_as_float(p0 << 16)
               + __int_as_float(m0.w) * __uint_as_float(p0 & 0xFFFF0000u)) * x0;
    }
    agg[(size_t)n * HD + t] = acc0 + acc1;
}

// ================= mean pool =================
__global__ void pool_kernel(const float* __restrict__ h1, const int* __restrict__ batch,
                            float* __restrict__ gsum, float* __restrict__ gcnt, int N) {
    __shared__ float pool[NGRAPH][HD];
    __shared__ float cnt[NGRAPH];
    const int t = threadIdx.x;
    #pragma unroll
    for (int g = 0; g < NGRAPH; ++g) pool[g][t] = 0.0f;
    if (t < NGRAPH) cnt[t] = 0.0f;
    __syncthreads();
    int chunk = (N + gridDim.x - 1) / gridDim.x;
    int n0 = blockIdx.x * chunk, n1 = min(N, n0 + chunk);
    for (int n = n0; n < n1; ++n) {
        int b = batch[n];
        pool[b][t] += h1[(size_t)n * HD + t];
        if (t == 0) cnt[b] += 1.0f;
    }
    __syncthreads();
    #pragma unroll
    for (int g = 0; g < NGRAPH; ++g) atomicAdd(&gsum[g*HD + t], pool[g][t]);
    if (t < NGRAPH) atomicAdd(&gcnt[t], cnt[t]);
}

// ================= head =================
__global__ void finalize_kernel(const float* __restrict__ gsum, const float* __restrict__ gcnt,
                                const float* __restrict__ l1w, const float* __restrict__ l1b,
                                const float* __restrict__ l2w, const float* __restrict__ l2b,
                                float* __restrict__ d_out) {
    __shared__ float ge[HD];
    __shared__ float h2[HD];
    const int g = blockIdx.x, t = threadIdx.x;
    float cnt = fmaxf(gcnt[g], 1.0f);
    float v = gsum[g*HD + t] / cnt;
    d_out[g*HD + t] = v;
    ge[t] = v;
    __syncthreads();
    float acc = l1b[t];
    #pragma unroll 8
    for (int k = 0; k < HD; ++k) acc += ge[k] * l1w[k*HD + t];
    h2[t] = fmaxf(acc, 0.0f);
    __syncthreads();
    if (t < NCLS) {
        float o = l2b[t];
        #pragma unroll 8
        for (int k = 0; k < HD; ++k) o += h2[k] * l2w[k*NCLS + t];
        d_out[NGRAPH*HD + g*NCLS + t] = o;
    }
}

extern "C" void kernel_launch(void* const* d_in, const int* in_sizes, int n_in,
                              void* d_out, int out_size, void* d_ws, size_t ws_size,
                              hipStream_t stream) {
    const float* x     = (const float*)d_in[0];
    const float* pos   = (const float*)d_in[1];
    const int*   eidx  = (const int*)d_in[2];
    const int*   batch = (const int*)d_in[3];
    const float* emb_w = (const float*)d_in[4];
    const float* emb_b = (const float*)d_in[5];
    const float* m1w   = (const float*)d_in[6];
    const float* m1b   = (const float*)d_in[7];
    const float* m2w   = (const float*)d_in[8];
    const float* m2b   = (const float*)d_in[9];
    const float* c1w   = (const float*)d_in[10];
    const float* c2w   = (const float*)d_in[11];
    const float* c2b   = (const float*)d_in[12];
    const float* lw    = (const float*)d_in[13];
    const float* lb    = (const float*)d_in[14];
    const float* l1w   = (const float*)d_in[15];
    const float* l1b   = (const float*)d_in[16];
    const float* l2w   = (const float*)d_in[17];
    const float* l2b   = (const float*)d_in[18];

    const int N = in_sizes[0] / 21;          // 20000
    const int E = in_sizes[2] / 2;           // 640000
    const int* row = eidx;
    const int* col = eidx + E;
    const int NT   = (N + 127) / 128;        // 157
    const int Npad = NT * 128;

    size_t off = 0;
    char* base = (char*)d_ws;
    auto alloc = [&](size_t bytes) -> void* {
        off = (off + 255) & ~(size_t)255;
        void* p = base + off;
        off += bytes;
        return p;
    };
    int*    deg     = (int*)alloc((size_t)N * 4);
    int*    cursor  = (int*)alloc((size_t)N * 4);
    int*    rowp    = (int*)alloc((size_t)(N + 1) * 4);
    int4*   meta    = (int4*)alloc((size_t)E * 16);
    float*  h       = (float*)alloc((size_t)Npad * HD * 4);
    float*  hx      = (float*)alloc((size_t)Npad * HD * 4);
    float*  agg     = (float*)alloc((size_t)Npad * HD * 4);
    float*  h1      = (float*)alloc((size_t)Npad * HD * 4);
    float*  T6      = (float*)alloc((size_t)6 * NTAB * HD * 4);
    uint*   P6      = (uint*)alloc((size_t)6 * NTAB * HD * 4);
    ushort* m1T     = (ushort*)alloc((size_t)6 * 128 * 64 * 2);
    ushort* nodeThi = (ushort*)alloc((size_t)19 * 128 * 128 * 2);
    ushort* nodeTlo = (ushort*)alloc((size_t)19 * 128 * 128 * 2);
    ushort* m2T     = (ushort*)alloc((size_t)6 * 128 * 128 * 2);
    float*  gsum    = (float*)alloc((size_t)NGRAPH * HD * 4);
    float*  gcnt    = (float*)alloc((size_t)NGRAPH * 4);

    // ---- one-time: weight prep + CSR + all 6 filter tables ----
    prep_kernel<<<1792, 256, 0, stream>>>(m1w, c1w, c2w, lw, l1w, m2w,
                                          m1T, nodeThi, nodeTlo, m2T);
    hipMemsetAsync(deg, 0, (size_t)N * 4, stream);
    hist_kernel<<<(E + 255)/256, 256, 0, stream>>>(col, deg, E);
    scan_kernel<<<1, 256, 0, stream>>>(deg, rowp, cursor, N);
    fill_kernel<<<(E + 255)/256, 256, 0, stream>>>(row, col, pos, cursor, meta, E);
    buildtab_kernel<<<6 * (NTAB/128), 256, 0, stream>>>(m1T, m2T, m1b, m2b, T6);
    packtab_kernel<<<(6*NTAB*HD + 255)/256, 256, 0, stream>>>(T6, P6);
    embed_kernel<<<(N*HD + 255)/256, 256, 0, stream>>>(x, emb_w, emb_b, h, N);

    for (int l = 0; l < NLAYER; ++l) {
        const ushort* c1Thi = nodeThi + (size_t)l * 16384;
        const ushort* c1Tlo = nodeTlo + (size_t)l * 16384;
        const ushort* c2Thi = nodeThi + (size_t)(6 + l) * 16384;
        const ushort* c2Tlo = nodeTlo + (size_t)(6 + l) * 16384;
        const ushort* lThi  = nodeThi + (size_t)(12 + l) * 16384;
        const ushort* lTlo  = nodeTlo + (size_t)(12 + l) * 16384;

        // hx = h @ c1w
        gemm_kernel<128, 0, 0, true><<<NT, 256, 0, stream>>>(
            h, c1Thi, c1Tlo, nullptr, hx, nullptr, NT);
        // agg[n] = sum_s lerp(T_l, w_s)*cenv_s*hx[row_s]
        gathersum_kernel<<<N, HD, 0, stream>>>(
            P6 + (size_t)l * NTAB * HD, meta, rowp, hx, agg, N);
        // h += ssp(agg@c2+c2b)@lw + lb   (fused, tmp in LDS)
        nodefused_kernel<<<NT, 256, 0, stream>>>(
            agg, c2Thi, c2Tlo, c2b + l*HD, lThi, lTlo, lb + l*HD, h, NT);
    }

    // h1 = relu(h @ lin1 + b1)
    gemm_kernel<128, 0, 4, true><<<NT, 256, 0, stream>>>(
        h, nodeThi + (size_t)18 * 16384, nodeTlo + (size_t)18 * 16384,
        l1b, h1, nullptr, NT);

    hipMemsetAsync(gsum, 0, (size_t)(NGRAPH*HD + NGRAPH) * 4, stream);
    pool_kernel<<<256, HD, 0, stream>>>(h1, batch, gsum, gcnt, N);
    finalize_kernel<<<NGRAPH, HD, 0, stream>>>(gsum, gcnt, l1w, l1b, l2w, l2b,
                                               (float*)d_out);
}

// Round 7
// 726.275 us; speedup vs baseline: 93.9909x; 1.0548x over previous
//
#include <hip/hip_runtime.h>
#include <hip/hip_bf16.h>

#define HD 128
#define NGAUSS 50
#define NLAYER 6
#define NGRAPH 16
#define NCLS 97
#define NTAB 2048
#define WMAX 12.0f

typedef __attribute__((ext_vector_type(8))) short bf16x8;
typedef __attribute__((ext_vector_type(4))) float f32x4;
typedef __attribute__((ext_vector_type(8))) ushort u16x8;
typedef __attribute__((ext_vector_type(4))) ushort u16x4;

// fast shifted-softplus: softplus(x)-ln2 = max(x,0) + ln(0.5 + 0.5*exp(-|x|))
__device__ __forceinline__ float ssp_f(float x) {
    float e = __expf(-fabsf(x));
    return fmaxf(x, 0.0f) + __logf(0.5f + 0.5f * e);
}
__device__ __forceinline__ ushort f2bf(float f) {   // RNE f32->bf16
    uint u = __float_as_uint(f);
    return (ushort)((u + 0x7FFFu + ((u >> 16) & 1u)) >> 16);
}
__device__ __forceinline__ float bf2f(ushort s) {
    return __uint_as_float(((uint)s) << 16);
}

// ================= CSR build =================
__global__ void hist_kernel(const int* __restrict__ col, int* __restrict__ deg, int E) {
    int e = blockIdx.x * blockDim.x + threadIdx.x;
    if (e < E) atomicAdd(&deg[col[e]], 1);
}

__global__ void scan_kernel(const int* __restrict__ deg, int* __restrict__ rowp,
                            int* __restrict__ cursor, int N) {
    __shared__ int part[256];
    const int t = threadIdx.x;
    const int chunk = (N + 255) / 256;
    const int i0 = t * chunk, i1 = min(N, i0 + chunk);
    int s = 0;
    for (int i = i0; i < i1; ++i) s += deg[i];
    part[t] = s;
    __syncthreads();
    for (int off = 1; off < 256; off <<= 1) {
        int v = part[t];
        int add = (t >= off) ? part[t - off] : 0;
        __syncthreads();
        part[t] = v + add;
        __syncthreads();
    }
    int run = (t == 0) ? 0 : part[t - 1];
    for (int i = i0; i < i1; ++i) {
        rowp[i] = run; cursor[i] = run; run += deg[i];
    }
    if (t == 255) rowp[N] = run;
}

// per-slot metadata (8 B): word0 = row | (tab_idx<<16); word1 = bf16{(1-f)*cenv} | bf16{f*cenv}<<16
__global__ void fill_kernel(const int* __restrict__ row, const int* __restrict__ col,
                            const float* __restrict__ pos, int* __restrict__ cursor,
                            uint2* __restrict__ meta, int E) {
    int e = blockIdx.x * blockDim.x + threadIdx.x;
    if (e >= E) return;
    int c = col[e], r = row[e];
    int slot = atomicAdd(&cursor[c], 1);
    float dx = pos[r*3+0] - pos[c*3+0];
    float dy = pos[r*3+1] - pos[c*3+1];
    float dz = pos[r*3+2] - pos[c*3+2];
    float w = sqrtf(dx*dx + dy*dy + dz*dz);
    float cenv = 0.5f * (cosf(w * 0.31415926535897931f) + 1.0f);
    const float invDW = (float)(NTAB - 1) / WMAX;
    float tt = w * invDW;
    int i = min((int)tt, NTAB - 1);
    float f = fminf(tt - (float)i, 1.0f);
    uint w0 = ((uint)r) | (((uint)i) << 16);
    uint w1 = ((uint)f2bf((1.0f - f) * cenv)) | (((uint)f2bf(f * cenv)) << 16);
    meta[slot] = make_uint2(w0, w1);
}

// ================= weight prep: transpose + bf16 (hi/lo split for node mats) ========
__global__ void prep_kernel(const float* __restrict__ m1w, const float* __restrict__ c1w,
                            const float* __restrict__ c2w, const float* __restrict__ lw,
                            const float* __restrict__ l1w, const float* __restrict__ m2w,
                            ushort* __restrict__ m1T, ushort* __restrict__ nodeThi,
                            ushort* __restrict__ nodeTlo, ushort* __restrict__ m2T) {
    int idx = blockIdx.x * blockDim.x + threadIdx.x;
    const int S1 = 6*128*64, S2 = 19*128*128, S3 = 6*128*128;
    if (idx < S1) {
        int l = idx / 8192, r = idx % 8192, c = r / 64, k = r % 64;
        float v = (k < NGAUSS) ? m1w[(size_t)l*NGAUSS*128 + k*128 + c] : 0.0f;
        m1T[(size_t)l*8192 + c*64 + k] = f2bf(v);
    } else if (idx < S1 + S2) {
        int j = idx - S1;
        int m = j / 16384, r = j % 16384, c = r / 128, k = r % 128;
        const float* src;
        if (m < 6)       src = c1w + (size_t)m*16384;
        else if (m < 12) src = c2w + (size_t)(m-6)*16384;
        else if (m < 18) src = lw  + (size_t)(m-12)*16384;
        else             src = l1w;
        float v = src[k*128 + c];
        ushort hi = f2bf(v);
        nodeThi[(size_t)m*16384 + c*128 + k] = hi;
        nodeTlo[(size_t)m*16384 + c*128 + k] = f2bf(v - bf2f(hi));
    } else if (idx < S1 + S2 + S3) {
        int j = idx - S1 - S2;
        int l = j / 16384, r = j % 16384, c = r / 128, k = r % 128;
        m2T[(size_t)l*16384 + c*128 + k] = f2bf(m2w[(size_t)l*16384 + k*128 + c]);
    }
}

// ================= embedding =================
__global__ void embed_kernel(const float* __restrict__ x,
                             const float* __restrict__ emb_w, const float* __restrict__ emb_b,
                             float* __restrict__ h, int N) {
    int idx = blockIdx.x * blockDim.x + threadIdx.x;
    if (idx >= N * HD) return;
    int n = idx >> 7, t = idx & 127;
    float acc = emb_b[t];
    #pragma unroll
    for (int a = 0; a < 21; ++a) acc += x[n*21 + a] * emb_w[a*HD + t];
    h[idx] = acc;
}

// ================= filter table build (proven efilter structure, 2048-pt grid) ======
__global__ __launch_bounds__(256, 2) void buildtab_kernel(
        const ushort* __restrict__ m1T_all, const ushort* __restrict__ m2T_all,
        const float* __restrict__ m1b_all, const float* __restrict__ m2b_all,
        float* __restrict__ T6) {
    __shared__ ushort A1[128 * 64];
    __shared__ ushort B1[128 * 64];
    __shared__ ushort U [128 * 128];
    char* A1b = (char*)A1;
    char* B1b = (char*)B1;
    char* Ub  = (char*)U;
    const int tid  = threadIdx.x;
    const int lane = tid & 63;
    const int wave = tid >> 6;
    const int l15  = lane & 15;
    const int kgrp = (lane >> 4) * 8;
    const int rbase = wave * 32;
    const int layer = blockIdx.x >> 4;
    const int mt    = blockIdx.x & 15;
    const ushort* m1T = m1T_all + (size_t)layer * 8192;
    const ushort* m2T = m2T_all + (size_t)layer * 16384;
    const float*  m1b = m1b_all + layer * HD;
    const float*  m2b = m2b_all + layer * HD;

    #pragma unroll
    for (int p = 0; p < 4; ++p) {
        int rr = p * 32 + (tid >> 3);
        int k8 = (tid & 7) * 8;
        u16x8 v = *reinterpret_cast<const u16x8*>(&m1T[(size_t)rr * 64 + k8]);
        *reinterpret_cast<u16x8*>(&B1b[rr*128 + ((2*k8) ^ ((rr & 7) << 4))]) = v;
    }

    float b1c[8], b2c[8];
    #pragma unroll
    for (int cb = 0; cb < 8; ++cb) { b1c[cb] = m1b[cb*16 + l15]; b2c[cb] = m2b[cb*16 + l15]; }

    const float step = 10.0f / 49.0f;
    const float coeff = -0.5f / (step * step);
    const float DW = WMAX / (float)(NTAB - 1);

    #pragma unroll
    for (int p = 0; p < 4; ++p) {
        int rr = p * 32 + (tid >> 3);
        int k8 = (tid & 7) * 8;
        float w = (float)(mt*128 + rr) * DW;
        u16x8 v;
        #pragma unroll
        for (int j = 0; j < 8; ++j) {
            int k = k8 + j;
            float d = w - (float)k * step;
            float g = (k < NGAUSS) ? __expf(coeff * d * d) : 0.0f;
            v[j] = f2bf(g);
        }
        *reinterpret_cast<u16x8*>(&A1b[rr*128 + ((2*k8) ^ ((rr & 7) << 4))]) = v;
    }
    __syncthreads();

    f32x4 acc1[2][8];
    #pragma unroll
    for (int i = 0; i < 2; ++i)
        #pragma unroll
        for (int j = 0; j < 8; ++j) { acc1[i][j].x=0.f; acc1[i][j].y=0.f; acc1[i][j].z=0.f; acc1[i][j].w=0.f; }
    #pragma unroll
    for (int ks = 0; ks < 2; ++ks) {
        int k = ks*32 + kgrp;
        bf16x8 af[2];
        #pragma unroll
        for (int rt = 0; rt < 2; ++rt) {
            int r = rbase + rt*16 + l15;
            af[rt] = *reinterpret_cast<const bf16x8*>(&A1b[r*128 + ((2*k) ^ ((r & 7) << 4))]);
        }
        #pragma unroll
        for (int cb = 0; cb < 8; ++cb) {
            int c = cb*16 + l15;
            bf16x8 bv = *reinterpret_cast<const bf16x8*>(&B1b[c*128 + ((2*k) ^ ((c & 7) << 4))]);
            acc1[0][cb] = __builtin_amdgcn_mfma_f32_16x16x32_bf16(af[0], bv, acc1[0][cb], 0, 0, 0);
            acc1[1][cb] = __builtin_amdgcn_mfma_f32_16x16x32_bf16(af[1], bv, acc1[1][cb], 0, 0, 0);
        }
    }
    #pragma unroll
    for (int rt = 0; rt < 2; ++rt) {
        #pragma unroll
        for (int cb = 0; cb < 8; ++cb) {
            int c = cb*16 + l15;
            #pragma unroll
            for (int i = 0; i < 4; ++i) {
                int rrow = rbase + rt*16 + (lane >> 4)*4 + i;
                ushort us = f2bf(ssp_f(acc1[rt][cb][i] + b1c[cb]));
                *reinterpret_cast<ushort*>(&Ub[rrow*256 + ((2*c) ^ ((rrow & 7) << 4))]) = us;
            }
        }
    }
    __syncthreads();

    f32x4 acc2[2][8];
    #pragma unroll
    for (int i = 0; i < 2; ++i)
        #pragma unroll
        for (int j = 0; j < 8; ++j) { acc2[i][j].x=0.f; acc2[i][j].y=0.f; acc2[i][j].z=0.f; acc2[i][j].w=0.f; }
    #pragma unroll
    for (int kh = 0; kh < 2; ++kh) {
        if (kh) __syncthreads();
        #pragma unroll
        for (int p = 0; p < 4; ++p) {
            int rr = p * 32 + (tid >> 3);
            int kk = (tid & 7) * 8;
            u16x8 v = *reinterpret_cast<const u16x8*>(&m2T[(size_t)rr*128 + kh*64 + kk]);
            *reinterpret_cast<u16x8*>(&A1b[rr*128 + ((2*kk) ^ ((rr & 7) << 4))]) = v;
        }
        __syncthreads();
        #pragma unroll
        for (int ks2 = 0; ks2 < 2; ++ks2) {
            int ku = kh*64 + ks2*32 + kgrp;
            int kb = ks2*32 + kgrp;
            bf16x8 af[2];
            #pragma unroll
            for (int rt = 0; rt < 2; ++rt) {
                int r = rbase + rt*16 + l15;
                af[rt] = *reinterpret_cast<const bf16x8*>(&Ub[r*256 + ((2*ku) ^ ((r & 7) << 4))]);
            }
            #pragma unroll
            for (int cb = 0; cb < 8; ++cb) {
                int c = cb*16 + l15;
                bf16x8 bv = *reinterpret_cast<const bf16x8*>(&A1b[c*128 + ((2*kb) ^ ((c & 7) << 4))]);
                acc2[0][cb] = __builtin_amdgcn_mfma_f32_16x16x32_bf16(af[0], bv, acc2[0][cb], 0, 0, 0);
                acc2[1][cb] = __builtin_amdgcn_mfma_f32_16x16x32_bf16(af[1], bv, acc2[1][cb], 0, 0, 0);
            }
        }
    }

    #pragma unroll
    for (int rt = 0; rt < 2; ++rt) {
        #pragma unroll
        for (int cb = 0; cb < 8; ++cb) {
            int c = cb*16 + l15;
            #pragma unroll
            for (int i = 0; i < 4; ++i) {
                int rrow = rbase + rt*16 + (lane >> 4)*4 + i;
                T6[((size_t)layer*NTAB + mt*128 + rrow) * HD + c] = acc2[rt][cb][i] + b2c[cb];
            }
        }
    }
}

// pack table rows i,i+1 as {bf16,bf16} in one u32
__global__ void packtab_kernel(const float* __restrict__ T6, uint* __restrict__ P6) {
    int idx = blockIdx.x * blockDim.x + threadIdx.x;
    if (idx >= 6 * NTAB * HD) return;
    int r = (idx >> 7) & (NTAB - 1);
    float v0 = T6[idx];
    float v1 = (r + 1 < NTAB) ? T6[idx + HD] : v0;
    P6[idx] = ((uint)f2bf(v0)) | (((uint)f2bf(v1)) << 16);
}

// ================= 64-row-tile GEMV: out = EPI(h[64,128] @ (Bhi+Blo)) =================
// EPI 4: bias + relu -> f32 ; EPI 5: no bias -> bf16
// LDS 48 KB -> 3 blocks/CU; grid = ceil(rows/64).
template<int EPI>
__global__ __launch_bounds__(256) void gemv64_kernel(
        const float* __restrict__ A, const ushort* __restrict__ BThi,
        const ushort* __restrict__ BTlo, const float* __restrict__ bias,
        float* __restrict__ fdst, ushort* __restrict__ bdst, int mtiles) {
    __shared__ ushort A_[64 * 128];
    __shared__ ushort B_[128 * 128];
    char* Ab = (char*)A_;
    char* Bb = (char*)B_;
    const int tid  = threadIdx.x;
    const int lane = tid & 63;
    const int wave = tid >> 6;
    const int l15  = lane & 15;
    const int kgrp = (lane >> 4) * 8;
    const int rbase = wave * 16;

    for (int mt = blockIdx.x; mt < mtiles; mt += gridDim.x) {
        __syncthreads();
        // stage A (f32 -> bf16, swizzled)
        #pragma unroll
        for (int p = 0; p < 8; ++p) {
            int rr = p * 8 + (tid >> 5);
            int k4 = (tid & 31) * 4;
            f32x4 v = *reinterpret_cast<const f32x4*>(&A[(size_t)(mt*64 + rr)*HD + k4]);
            u16x4 b;
            b.x = f2bf(v.x); b.y = f2bf(v.y); b.z = f2bf(v.z); b.w = f2bf(v.w);
            *reinterpret_cast<u16x4*>(&Ab[rr*256 + ((2*k4) ^ ((rr & 7) << 4))]) = b;
        }

        f32x4 acc[8];
        #pragma unroll
        for (int j = 0; j < 8; ++j) { acc[j].x=0.f; acc[j].y=0.f; acc[j].z=0.f; acc[j].w=0.f; }

        #pragma unroll
        for (int part = 0; part < 2; ++part) {
            const ushort* BT = part ? BTlo : BThi;
            __syncthreads();      // part0: A visible; part1: prior B reads done
            #pragma unroll
            for (int p = 0; p < 8; ++p) {
                int rr = p * 16 + (tid >> 4);
                int k8 = (tid & 15) * 8;
                u16x8 v = *reinterpret_cast<const u16x8*>(&BT[(size_t)rr*128 + k8]);
                *reinterpret_cast<u16x8*>(&Bb[rr*256 + ((2*k8) ^ ((rr & 7) << 4))]) = v;
            }
            __syncthreads();
            #pragma unroll
            for (int ks = 0; ks < 4; ++ks) {
                int k = ks*32 + kgrp;
                int r = rbase + l15;
                bf16x8 af = *reinterpret_cast<const bf16x8*>(&Ab[r*256 + ((2*k) ^ ((r & 7) << 4))]);
                #pragma unroll
                for (int cb = 0; cb < 8; ++cb) {
                    int c = cb*16 + l15;
                    bf16x8 bv = *reinterpret_cast<const bf16x8*>(&Bb[c*256 + ((2*k) ^ ((c & 7) << 4))]);
                    acc[cb] = __builtin_amdgcn_mfma_f32_16x16x32_bf16(af, bv, acc[cb], 0, 0, 0);
                }
            }
        }

        #pragma unroll
        for (int cb = 0; cb < 8; ++cb) {
            int c = cb*16 + l15;
            float bt = (EPI == 4) ? bias[c] : 0.0f;
            #pragma unroll
            for (int i = 0; i < 4; ++i) {
                int row = mt*64 + rbase + (lane >> 4)*4 + i;
                size_t off = (size_t)row * HD + c;
                float v = acc[cb][i];
                if (EPI == 4) fdst[off] = fmaxf(v + bt, 0.0f);
                else          bdst[off] = f2bf(v);
            }
        }
    }
}

// ================= fused node block (64-row): h += ssp(agg@c2+c2b)@lw + lb =========
// agg input bf16. LDS 64 KB -> 2 blocks/CU.
__global__ __launch_bounds__(256) void nodefused_kernel(
        const ushort* __restrict__ aggb,
        const ushort* __restrict__ c2hi, const ushort* __restrict__ c2lo,
        const float* __restrict__ c2b,
        const ushort* __restrict__ lwhi, const ushort* __restrict__ lwlo,
        const float* __restrict__ lb,
        float* __restrict__ h, int mtiles) {
    __shared__ ushort A_[64 * 128];
    __shared__ ushort B_[128 * 128];
    __shared__ ushort U_[64 * 128];
    char* Ab = (char*)A_;
    char* Bb = (char*)B_;
    char* Ub = (char*)U_;
    const int tid  = threadIdx.x;
    const int lane = tid & 63;
    const int wave = tid >> 6;
    const int l15  = lane & 15;
    const int kgrp = (lane >> 4) * 8;
    const int rbase = wave * 16;

    float b1c[8], b2c[8];
    #pragma unroll
    for (int cb = 0; cb < 8; ++cb) { b1c[cb] = c2b[cb*16 + l15]; b2c[cb] = lb[cb*16 + l15]; }

    for (int mt = blockIdx.x; mt < mtiles; mt += gridDim.x) {
        __syncthreads();
        // stage A = agg tile (bf16, swizzled)
        #pragma unroll
        for (int p = 0; p < 4; ++p) {
            int rr = p * 16 + (tid >> 4);
            int k8 = (tid & 15) * 8;
            u16x8 v = *reinterpret_cast<const u16x8*>(&aggb[(size_t)(mt*64 + rr)*HD + k8]);
            *reinterpret_cast<u16x8*>(&Ab[rr*256 + ((2*k8) ^ ((rr & 7) << 4))]) = v;
        }

        // ---- GEMM1: acc = A @ (c2hi+c2lo) ----
        f32x4 acc[8];
        #pragma unroll
        for (int j = 0; j < 8; ++j) { acc[j].x=0.f; acc[j].y=0.f; acc[j].z=0.f; acc[j].w=0.f; }
        #pragma unroll
        for (int part = 0; part < 2; ++part) {
            const ushort* BT = part ? c2lo : c2hi;
            __syncthreads();
            #pragma unroll
            for (int p = 0; p < 8; ++p) {
                int rr = p * 16 + (tid >> 4);
                int k8 = (tid & 15) * 8;
                u16x8 v = *reinterpret_cast<const u16x8*>(&BT[(size_t)rr*128 + k8]);
                *reinterpret_cast<u16x8*>(&Bb[rr*256 + ((2*k8) ^ ((rr & 7) << 4))]) = v;
            }
            __syncthreads();
            #pragma unroll
            for (int ks = 0; ks < 4; ++ks) {
                int k = ks*32 + kgrp;
                int r = rbase + l15;
                bf16x8 af = *reinterpret_cast<const bf16x8*>(&Ab[r*256 + ((2*k) ^ ((r & 7) << 4))]);
                #pragma unroll
                for (int cb = 0; cb < 8; ++cb) {
                    int c = cb*16 + l15;
                    bf16x8 bv = *reinterpret_cast<const bf16x8*>(&Bb[c*256 + ((2*k) ^ ((c & 7) << 4))]);
                    acc[cb] = __builtin_amdgcn_mfma_f32_16x16x32_bf16(af, bv, acc[cb], 0, 0, 0);
                }
            }
        }
        // epilogue1: ssp -> U
        #pragma unroll
        for (int cb = 0; cb < 8; ++cb) {
            int c = cb*16 + l15;
            #pragma unroll
            for (int i = 0; i < 4; ++i) {
                int rrow = rbase + (lane >> 4)*4 + i;
                ushort us = f2bf(ssp_f(acc[cb][i] + b1c[cb]));
                *reinterpret_cast<ushort*>(&Ub[rrow*256 + ((2*c) ^ ((rrow & 7) << 4))]) = us;
            }
        }

        // ---- GEMM2: acc = U @ (lwhi+lwlo) ----
        #pragma unroll
        for (int j = 0; j < 8; ++j) { acc[j].x=0.f; acc[j].y=0.f; acc[j].z=0.f; acc[j].w=0.f; }
        #pragma unroll
        for (int part = 0; part < 2; ++part) {
            const ushort* BT = part ? lwlo : lwhi;
            __syncthreads();     // part0: U visible + GEMM1 B reads done
            #pragma unroll
            for (int p = 0; p < 8; ++p) {
                int rr = p * 16 + (tid >> 4);
                int k8 = (tid & 15) * 8;
                u16x8 v = *reinterpret_cast<const u16x8*>(&BT[(size_t)rr*128 + k8]);
                *reinterpret_cast<u16x8*>(&Bb[rr*256 + ((2*k8) ^ ((rr & 7) << 4))]) = v;
            }
            __syncthreads();
            #pragma unroll
            for (int ks = 0; ks < 4; ++ks) {
                int k = ks*32 + kgrp;
                int r = rbase + l15;
                bf16x8 af = *reinterpret_cast<const bf16x8*>(&Ub[r*256 + ((2*k) ^ ((r & 7) << 4))]);
                #pragma unroll
                for (int cb = 0; cb < 8; ++cb) {
                    int c = cb*16 + l15;
                    bf16x8 bv = *reinterpret_cast<const bf16x8*>(&Bb[c*256 + ((2*k) ^ ((c & 7) << 4))]);
                    acc[cb] = __builtin_amdgcn_mfma_f32_16x16x32_bf16(af, bv, acc[cb], 0, 0, 0);
                }
            }
        }
        // epilogue2: h += acc + lb
        #pragma unroll
        for (int cb = 0; cb < 8; ++cb) {
            int c = cb*16 + l15;
            #pragma unroll
            for (int i = 0; i < 4; ++i) {
                int row = mt*64 + rbase + (lane >> 4)*4 + i;
                size_t off = (size_t)row * HD + c;
                h[off] = h[off] + acc[cb][i] + b2c[cb];
            }
        }
    }
}

// ================= fused gather-lerp-segment-sum (bf16 hx, bf16 agg out) ============
// 4 nodes per 256-thread block, one wave per node; lane owns cols {2l, 2l+1}.
__global__ __launch_bounds__(256) void gathersum_kernel(
        const uint* __restrict__ Tp, const uint2* __restrict__ meta,
        const int* __restrict__ rowp, const ushort* __restrict__ hxb,
        ushort* __restrict__ aggb, int N) {
    const int lane = threadIdx.x & 63;
    const int n = blockIdx.x * 4 + (threadIdx.x >> 6);
    if (n >= N) return;
    const int c0 = lane * 2;
    const int s0 = rowp[n], s1 = rowp[n + 1];
    float a0 = 0.f, a1 = 0.f, b0 = 0.f, b1 = 0.f;
    int s = s0;
    for (; s + 2 <= s1; s += 2) {
        uint2 m0 = meta[s];
        uint2 m1 = meta[s + 1];
        uint2 tp0 = *reinterpret_cast<const uint2*>(&Tp[(size_t)(m0.x >> 16) * HD + c0]);
        uint  hv0 = *reinterpret_cast<const uint*>(&hxb[(size_t)(m0.x & 0xFFFFu) * HD + c0]);
        uint2 tp1 = *reinterpret_cast<const uint2*>(&Tp[(size_t)(m1.x >> 16) * HD + c0]);
        uint  hv1 = *reinterpret_cast<const uint*>(&hxb[(size_t)(m1.x & 0xFFFFu) * HD + c0]);
        float w0a = bf2f((ushort)(m0.y & 0xFFFFu)), w0b = bf2f((ushort)(m0.y >> 16));
        float w1a = bf2f((ushort)(m1.y & 0xFFFFu)), w1b = bf2f((ushort)(m1.y >> 16));
        float g00 = w0a * __uint_as_float(tp0.x << 16) + w0b * __uint_as_float(tp0.x & 0xFFFF0000u);
        float g01 = w0a * __uint_as_float(tp0.y << 16) + w0b * __uint_as_float(tp0.y & 0xFFFF0000u);
        float g10 = w1a * __uint_as_float(tp1.x << 16) + w1b * __uint_as_float(tp1.x & 0xFFFF0000u);
        float g11 = w1a * __uint_as_float(tp1.y << 16) + w1b * __uint_as_float(tp1.y & 0xFFFF0000u);
        a0 += g00 * bf2f((ushort)(hv0 & 0xFFFFu));
        a1 += g01 * bf2f((ushort)(hv0 >> 16));
        b0 += g10 * bf2f((ushort)(hv1 & 0xFFFFu));
        b1 += g11 * bf2f((ushort)(hv1 >> 16));
    }
    if (s < s1) {
        uint2 m0 = meta[s];
        uint2 tp0 = *reinterpret_cast<const uint2*>(&Tp[(size_t)(m0.x >> 16) * HD + c0]);
        uint  hv0 = *reinterpret_cast<const uint*>(&hxb[(size_t)(m0.x & 0xFFFFu) * HD + c0]);
        float w0a = bf2f((ushort)(m0.y & 0xFFFFu)), w0b = bf2f((ushort)(m0.y >> 16));
        float g00 = w0a * __uint_as_float(tp0.x << 16) + w0b * __uint_as_float(tp0.x & 0xFFFF0000u);
        float g01 = w0a * __uint_as_float(tp0.y << 16) + w0b * __uint_as_float(tp0.y & 0xFFFF0000u);
        a0 += g00 * bf2f((ushort)(hv0 & 0xFFFFu));
        a1 += g01 * bf2f((ushort)(hv0 >> 16));
    }
    uint out = ((uint)f2bf(a0 + b0)) | (((uint)f2bf(a1 + b1)) << 16);
    *reinterpret_cast<uint*>(&aggb[(size_t)n * HD + c0]) = out;
}

// ================= mean pool =================
__global__ void pool_kernel(const float* __restrict__ h1, const int* __restrict__ batch,
                            float* __restrict__ gsum, float* __restrict__ gcnt, int N) {
    __shared__ float pool[NGRAPH][HD];
    __shared__ float cnt[NGRAPH];
    const int t = threadIdx.x;
    #pragma unroll
    for (int g = 0; g < NGRAPH; ++g) pool[g][t] = 0.0f;
    if (t < NGRAPH) cnt[t] = 0.0f;
    __syncthreads();
    int chunk = (N + gridDim.x - 1) / gridDim.x;
    int n0 = blockIdx.x * chunk, n1 = min(N, n0 + chunk);
    for (int n = n0; n < n1; ++n) {
        int b = batch[n];
        pool[b][t] += h1[(size_t)n * HD + t];
        if (t == 0) cnt[b] += 1.0f;
    }
    __syncthreads();
    #pragma unroll
    for (int g = 0; g < NGRAPH; ++g) atomicAdd(&gsum[g*HD + t], pool[g][t]);
    if (t < NGRAPH) atomicAdd(&gcnt[t], cnt[t]);
}

// ================= head =================
__global__ void finalize_kernel(const float* __restrict__ gsum, const float* __restrict__ gcnt,
                                const float* __restrict__ l1w, const float* __restrict__ l1b,
                                const float* __restrict__ l2w, const float* __restrict__ l2b,
                                float* __restrict__ d_out) {
    __shared__ float ge[HD];
    __shared__ float h2[HD];
    const int g = blockIdx.x, t = threadIdx.x;
    float cnt = fmaxf(gcnt[g], 1.0f);
    float v = gsum[g*HD + t] / cnt;
    d_out[g*HD + t] = v;
    ge[t] = v;
    __syncthreads();
    float acc = l1b[t];
    #pragma unroll 8
    for (int k = 0; k < HD; ++k) acc += ge[k] * l1w[k*HD + t];
    h2[t] = fmaxf(acc, 0.0f);
    __syncthreads();
    if (t < NCLS) {
        float o = l2b[t];
        #pragma unroll 8
        for (int k = 0; k < HD; ++k) o += h2[k] * l2w[k*NCLS + t];
        d_out[NGRAPH*HD + g*NCLS + t] = o;
    }
}

extern "C" void kernel_launch(void* const* d_in, const int* in_sizes, int n_in,
                              void* d_out, int out_size, void* d_ws, size_t ws_size,
                              hipStream_t stream) {
    const float* x     = (const float*)d_in[0];
    const float* pos   = (const float*)d_in[1];
    const int*   eidx  = (const int*)d_in[2];
    const int*   batch = (const int*)d_in[3];
    const float* emb_w = (const float*)d_in[4];
    const float* emb_b = (const float*)d_in[5];
    const float* m1w   = (const float*)d_in[6];
    const float* m1b   = (const float*)d_in[7];
    const float* m2w   = (const float*)d_in[8];
    const float* m2b   = (const float*)d_in[9];
    const float* c1w   = (const float*)d_in[10];
    const float* c2w   = (const float*)d_in[11];
    const float* c2b   = (const float*)d_in[12];
    const float* lw    = (const float*)d_in[13];
    const float* lb    = (const float*)d_in[14];
    const float* l1w   = (const float*)d_in[15];
    const float* l1b   = (const float*)d_in[16];
    const float* l2w   = (const float*)d_in[17];
    const float* l2b   = (const float*)d_in[18];

    const int N = in_sizes[0] / 21;          // 20000
    const int E = in_sizes[2] / 2;           // 640000
    const int* row = eidx;
    const int* col = eidx + E;
    const int NT64 = (N + 63) / 64;          // 313
    const int Npad = ((N + 127) / 128) * 128;

    size_t off = 0;
    char* base = (char*)d_ws;
    auto alloc = [&](size_t bytes) -> void* {
        off = (off + 255) & ~(size_t)255;
        void* p = base + off;
        off += bytes;
        return p;
    };
    int*    deg     = (int*)alloc((size_t)N * 4);
    int*    cursor  = (int*)alloc((size_t)N * 4);
    int*    rowp    = (int*)alloc((size_t)(N + 1) * 4);
    uint2*  meta    = (uint2*)alloc((size_t)E * 8);
    float*  h       = (float*)alloc((size_t)Npad * HD * 4);
    ushort* hxb     = (ushort*)alloc((size_t)Npad * HD * 2);
    ushort* aggb    = (ushort*)alloc((size_t)Npad * HD * 2);
    float*  h1      = (float*)alloc((size_t)Npad * HD * 4);
    float*  T6      = (float*)alloc((size_t)6 * NTAB * HD * 4);
    uint*   P6      = (uint*)alloc((size_t)6 * NTAB * HD * 4);
    ushort* m1T     = (ushort*)alloc((size_t)6 * 128 * 64 * 2);
    ushort* nodeThi = (ushort*)alloc((size_t)19 * 128 * 128 * 2);
    ushort* nodeTlo = (ushort*)alloc((size_t)19 * 128 * 128 * 2);
    ushort* m2T     = (ushort*)alloc((size_t)6 * 128 * 128 * 2);
    float*  gsum    = (float*)alloc((size_t)NGRAPH * HD * 4);
    float*  gcnt    = (float*)alloc((size_t)NGRAPH * 4);

    // ---- one-time: weight prep + CSR + filter tables ----
    prep_kernel<<<1792, 256, 0, stream>>>(m1w, c1w, c2w, lw, l1w, m2w,
                                          m1T, nodeThi, nodeTlo, m2T);
    hipMemsetAsync(deg, 0, (size_t)N * 4, stream);
    hist_kernel<<<(E + 255)/256, 256, 0, stream>>>(col, deg, E);
    scan_kernel<<<1, 256, 0, stream>>>(deg, rowp, cursor, N);
    fill_kernel<<<(E + 255)/256, 256, 0, stream>>>(row, col, pos, cursor, meta, E);
    buildtab_kernel<<<6 * (NTAB/128), 256, 0, stream>>>(m1T, m2T, m1b, m2b, T6);
    packtab_kernel<<<(6*NTAB*HD + 255)/256, 256, 0, stream>>>(T6, P6);
    embed_kernel<<<(N*HD + 255)/256, 256, 0, stream>>>(x, emb_w, emb_b, h, N);

    for (int l = 0; l < NLAYER; ++l) {
        const ushort* c1Thi = nodeThi + (size_t)l * 16384;
        const ushort* c1Tlo = nodeTlo + (size_t)l * 16384;
        const ushort* c2Thi = nodeThi + (size_t)(6 + l) * 16384;
        const ushort* c2Tlo = nodeTlo + (size_t)(6 + l) * 16384;
        const ushort* lThi  = nodeThi + (size_t)(12 + l) * 16384;
        const ushort* lTlo  = nodeTlo + (size_t)(12 + l) * 16384;

        // hxb = bf16(h @ c1w)
        gemv64_kernel<5><<<NT64, 256, 0, stream>>>(
            h, c1Thi, c1Tlo, nullptr, nullptr, hxb, NT64);
        // aggb[n] = bf16( sum_s lerp(T_l, w_s)*cenv_s*hx[row_s] )
        gathersum_kernel<<<(N + 3)/4, 256, 0, stream>>>(
            P6 + (size_t)l * NTAB * HD, meta, rowp, hxb, aggb, N);
        // h += ssp(aggb@c2+c2b)@lw + lb
        nodefused_kernel<<<NT64, 256, 0, stream>>>(
            aggb, c2Thi, c2Tlo, c2b + l*HD, lThi, lTlo, lb + l*HD, h, NT64);
    }

    // h1 = relu(h @ lin1 + b1)
    gemv64_kernel<4><<<NT64, 256, 0, stream>>>(
        h, nodeThi + (size_t)18 * 16384, nodeTlo + (size_t)18 * 16384,
        l1b, h1, nullptr, NT64);

    hipMemsetAsync(gsum, 0, (size_t)(NGRAPH*HD + NGRAPH) * 4, stream);
    pool_kernel<<<256, HD, 0, stream>>>(h1, batch, gsum, gcnt, N);
    finalize_kernel<<<NGRAPH, HD, 0, stream>>>(gsum, gcnt, l1w, l1b, l2w, l2b,
                                               (float*)d_out);
}

// Round 8
// 655.917 us; speedup vs baseline: 104.0729x; 1.1073x over previous
//
#include <hip/hip_runtime.h>
#include <hip/hip_bf16.h>

#define HD 128
#define NGAUSS 50
#define NLAYER 6
#define NGRAPH 16
#define NCLS 97
#define NTAB 2048
#define WMAX 12.0f

typedef __attribute__((ext_vector_type(8))) short bf16x8;
typedef __attribute__((ext_vector_type(4))) float f32x4;
typedef __attribute__((ext_vector_type(8))) ushort u16x8;
typedef __attribute__((ext_vector_type(4))) ushort u16x4;

__device__ __forceinline__ float ssp_f(float x) {
    float e = __expf(-fabsf(x));
    return fmaxf(x, 0.0f) + __logf(0.5f + 0.5f * e);
}
__device__ __forceinline__ ushort f2bf(float f) {   // RNE f32->bf16
    uint u = __float_as_uint(f);
    return (ushort)((u + 0x7FFFu + ((u >> 16) & 1u)) >> 16);
}
__device__ __forceinline__ float bf2f(ushort s) {
    return __uint_as_float(((uint)s) << 16);
}

// ================= CSR build =================
__global__ void hist_kernel(const int* __restrict__ col, int* __restrict__ deg, int E) {
    int e = blockIdx.x * blockDim.x + threadIdx.x;
    if (e < E) atomicAdd(&deg[col[e]], 1);
}

// 3-phase parallel scan (N <= 65536)
__global__ void scan1_kernel(const int* __restrict__ deg, int* __restrict__ rowp,
                             int* __restrict__ bsum, int N) {
    __shared__ int sm[256];
    const int t = threadIdx.x, i = blockIdx.x * 256 + t;
    int v = (i < N) ? deg[i] : 0;
    sm[t] = v;
    __syncthreads();
    for (int off = 1; off < 256; off <<= 1) {
        int x = sm[t];
        int a = (t >= off) ? sm[t - off] : 0;
        __syncthreads();
        sm[t] = x + a;
        __syncthreads();
    }
    if (i < N) rowp[i] = sm[t] - v;             // block-local exclusive
    if (t == 255) bsum[blockIdx.x] = sm[255];
}
__global__ void scan2_kernel(const int* __restrict__ bsum, int* __restrict__ boff,
                             int NB, int* __restrict__ rowpN) {
    __shared__ int sm[256];
    const int t = threadIdx.x;
    int v = (t < NB) ? bsum[t] : 0;
    sm[t] = v;
    __syncthreads();
    for (int off = 1; off < 256; off <<= 1) {
        int x = sm[t];
        int a = (t >= off) ? sm[t - off] : 0;
        __syncthreads();
        sm[t] = x + a;
        __syncthreads();
    }
    if (t < NB) boff[t] = sm[t] - v;            // exclusive block offsets
    if (t == 255) *rowpN = sm[255];             // total == E
}
__global__ void scan3_kernel(int* __restrict__ rowp, const int* __restrict__ boff,
                             int* __restrict__ cursor, int N) {
    int i = blockIdx.x * blockDim.x + threadIdx.x;
    if (i < N) {
        int r = rowp[i] + boff[i >> 8];
        rowp[i] = r;
        cursor[i] = r;
    }
}

// per-slot metadata (8 B): word0 = row | (tab_idx<<16); word1 = bf16{(1-f)*cenv} | bf16{f*cenv}<<16
__global__ void fill_kernel(const int* __restrict__ row, const int* __restrict__ col,
                            const float* __restrict__ pos, int* __restrict__ cursor,
                            uint2* __restrict__ meta, int E) {
    int e = blockIdx.x * blockDim.x + threadIdx.x;
    if (e >= E) return;
    int c = col[e], r = row[e];
    int slot = atomicAdd(&cursor[c], 1);
    float dx = pos[r*3+0] - pos[c*3+0];
    float dy = pos[r*3+1] - pos[c*3+1];
    float dz = pos[r*3+2] - pos[c*3+2];
    float w = sqrtf(dx*dx + dy*dy + dz*dz);
    float cenv = 0.5f * (cosf(w * 0.31415926535897931f) + 1.0f);
    const float invDW = (float)(NTAB - 1) / WMAX;
    float tt = w * invDW;
    int i = min((int)tt, NTAB - 1);
    float f = fminf(tt - (float)i, 1.0f);
    uint w0 = ((uint)r) | (((uint)i) << 16);
    uint w1 = ((uint)f2bf((1.0f - f) * cenv)) | (((uint)f2bf(f * cenv)) << 16);
    meta[slot] = make_uint2(w0, w1);
}

// ================= weight prep =================
__global__ void prep_kernel(const float* __restrict__ m1w, const float* __restrict__ c1w,
                            const float* __restrict__ c2w, const float* __restrict__ lw,
                            const float* __restrict__ l1w, const float* __restrict__ m2w,
                            ushort* __restrict__ m1T, ushort* __restrict__ nodeThi,
                            ushort* __restrict__ nodeTlo, ushort* __restrict__ m2T) {
    int idx = blockIdx.x * blockDim.x + threadIdx.x;
    const int S1 = 6*128*64, S2 = 19*128*128, S3 = 6*128*128;
    if (idx < S1) {
        int l = idx / 8192, r = idx % 8192, c = r / 64, k = r % 64;
        float v = (k < NGAUSS) ? m1w[(size_t)l*NGAUSS*128 + k*128 + c] : 0.0f;
        m1T[(size_t)l*8192 + c*64 + k] = f2bf(v);
    } else if (idx < S1 + S2) {
        int j = idx - S1;
        int m = j / 16384, r = j % 16384, c = r / 128, k = r % 128;
        const float* src;
        if (m < 6)       src = c1w + (size_t)m*16384;
        else if (m < 12) src = c2w + (size_t)(m-6)*16384;
        else if (m < 18) src = lw  + (size_t)(m-12)*16384;
        else             src = l1w;
        float v = src[k*128 + c];
        ushort hi = f2bf(v);
        nodeThi[(size_t)m*16384 + c*128 + k] = hi;
        nodeTlo[(size_t)m*16384 + c*128 + k] = f2bf(v - bf2f(hi));
    } else if (idx < S1 + S2 + S3) {
        int j = idx - S1 - S2;
        int l = j / 16384, r = j % 16384, c = r / 128, k = r % 128;
        m2T[(size_t)l*16384 + c*128 + k] = f2bf(m2w[(size_t)l*16384 + k*128 + c]);
    }
}

// ================= embedding =================
__global__ void embed_kernel(const float* __restrict__ x,
                             const float* __restrict__ emb_w, const float* __restrict__ emb_b,
                             float* __restrict__ h, int N) {
    int idx = blockIdx.x * blockDim.x + threadIdx.x;
    if (idx >= N * HD) return;
    int n = idx >> 7, t = idx & 127;
    float acc = emb_b[t];
    #pragma unroll
    for (int a = 0; a < 21; ++a) acc += x[n*21 + a] * emb_w[a*HD + t];
    h[idx] = acc;
}

// ================= filter table build (proven structure, 2048-pt grid) ======
__global__ __launch_bounds__(256, 2) void buildtab_kernel(
        const ushort* __restrict__ m1T_all, const ushort* __restrict__ m2T_all,
        const float* __restrict__ m1b_all, const float* __restrict__ m2b_all,
        float* __restrict__ T6) {
    __shared__ ushort A1[128 * 64];
    __shared__ ushort B1[128 * 64];
    __shared__ ushort U [128 * 128];
    char* A1b = (char*)A1;
    char* B1b = (char*)B1;
    char* Ub  = (char*)U;
    const int tid  = threadIdx.x;
    const int lane = tid & 63;
    const int wave = tid >> 6;
    const int l15  = lane & 15;
    const int kgrp = (lane >> 4) * 8;
    const int rbase = wave * 32;
    const int layer = blockIdx.x >> 4;
    const int mt    = blockIdx.x & 15;
    const ushort* m1T = m1T_all + (size_t)layer * 8192;
    const ushort* m2T = m2T_all + (size_t)layer * 16384;
    const float*  m1b = m1b_all + layer * HD;
    const float*  m2b = m2b_all + layer * HD;

    #pragma unroll
    for (int p = 0; p < 4; ++p) {
        int rr = p * 32 + (tid >> 3);
        int k8 = (tid & 7) * 8;
        u16x8 v = *reinterpret_cast<const u16x8*>(&m1T[(size_t)rr * 64 + k8]);
        *reinterpret_cast<u16x8*>(&B1b[rr*128 + ((2*k8) ^ ((rr & 7) << 4))]) = v;
    }

    float b1c[8], b2c[8];
    #pragma unroll
    for (int cb = 0; cb < 8; ++cb) { b1c[cb] = m1b[cb*16 + l15]; b2c[cb] = m2b[cb*16 + l15]; }

    const float step = 10.0f / 49.0f;
    const float coeff = -0.5f / (step * step);
    const float DW = WMAX / (float)(NTAB - 1);

    #pragma unroll
    for (int p = 0; p < 4; ++p) {
        int rr = p * 32 + (tid >> 3);
        int k8 = (tid & 7) * 8;
        float w = (float)(mt*128 + rr) * DW;
        u16x8 v;
        #pragma unroll
        for (int j = 0; j < 8; ++j) {
            int k = k8 + j;
            float d = w - (float)k * step;
            float g = (k < NGAUSS) ? __expf(coeff * d * d) : 0.0f;
            v[j] = f2bf(g);
        }
        *reinterpret_cast<u16x8*>(&A1b[rr*128 + ((2*k8) ^ ((rr & 7) << 4))]) = v;
    }
    __syncthreads();

    f32x4 acc1[2][8];
    #pragma unroll
    for (int i = 0; i < 2; ++i)
        #pragma unroll
        for (int j = 0; j < 8; ++j) { acc1[i][j].x=0.f; acc1[i][j].y=0.f; acc1[i][j].z=0.f; acc1[i][j].w=0.f; }
    #pragma unroll
    for (int ks = 0; ks < 2; ++ks) {
        int k = ks*32 + kgrp;
        bf16x8 af[2];
        #pragma unroll
        for (int rt = 0; rt < 2; ++rt) {
            int r = rbase + rt*16 + l15;
            af[rt] = *reinterpret_cast<const bf16x8*>(&A1b[r*128 + ((2*k) ^ ((r & 7) << 4))]);
        }
        #pragma unroll
        for (int cb = 0; cb < 8; ++cb) {
            int c = cb*16 + l15;
            bf16x8 bv = *reinterpret_cast<const bf16x8*>(&B1b[c*128 + ((2*k) ^ ((c & 7) << 4))]);
            acc1[0][cb] = __builtin_amdgcn_mfma_f32_16x16x32_bf16(af[0], bv, acc1[0][cb], 0, 0, 0);
            acc1[1][cb] = __builtin_amdgcn_mfma_f32_16x16x32_bf16(af[1], bv, acc1[1][cb], 0, 0, 0);
        }
    }
    #pragma unroll
    for (int rt = 0; rt < 2; ++rt) {
        #pragma unroll
        for (int cb = 0; cb < 8; ++cb) {
            int c = cb*16 + l15;
            #pragma unroll
            for (int i = 0; i < 4; ++i) {
                int rrow = rbase + rt*16 + (lane >> 4)*4 + i;
                ushort us = f2bf(ssp_f(acc1[rt][cb][i] + b1c[cb]));
                *reinterpret_cast<ushort*>(&Ub[rrow*256 + ((2*c) ^ ((rrow & 7) << 4))]) = us;
            }
        }
    }
    __syncthreads();

    f32x4 acc2[2][8];
    #pragma unroll
    for (int i = 0; i < 2; ++i)
        #pragma unroll
        for (int j = 0; j < 8; ++j) { acc2[i][j].x=0.f; acc2[i][j].y=0.f; acc2[i][j].z=0.f; acc2[i][j].w=0.f; }
    #pragma unroll
    for (int kh = 0; kh < 2; ++kh) {
        if (kh) __syncthreads();
        #pragma unroll
        for (int p = 0; p < 4; ++p) {
            int rr = p * 32 + (tid >> 3);
            int kk = (tid & 7) * 8;
            u16x8 v = *reinterpret_cast<const u16x8*>(&m2T[(size_t)rr*128 + kh*64 + kk]);
            *reinterpret_cast<u16x8*>(&A1b[rr*128 + ((2*kk) ^ ((rr & 7) << 4))]) = v;
        }
        __syncthreads();
        #pragma unroll
        for (int ks2 = 0; ks2 < 2; ++ks2) {
            int ku = kh*64 + ks2*32 + kgrp;
            int kb = ks2*32 + kgrp;
            bf16x8 af[2];
            #pragma unroll
            for (int rt = 0; rt < 2; ++rt) {
                int r = rbase + rt*16 + l15;
                af[rt] = *reinterpret_cast<const bf16x8*>(&Ub[r*256 + ((2*ku) ^ ((r & 7) << 4))]);
            }
            #pragma unroll
            for (int cb = 0; cb < 8; ++cb) {
                int c = cb*16 + l15;
                bf16x8 bv = *reinterpret_cast<const bf16x8*>(&A1b[c*128 + ((2*kb) ^ ((c & 7) << 4))]);
                acc2[0][cb] = __builtin_amdgcn_mfma_f32_16x16x32_bf16(af[0], bv, acc2[0][cb], 0, 0, 0);
                acc2[1][cb] = __builtin_amdgcn_mfma_f32_16x16x32_bf16(af[1], bv, acc2[1][cb], 0, 0, 0);
            }
        }
    }

    #pragma unroll
    for (int rt = 0; rt < 2; ++rt) {
        #pragma unroll
        for (int cb = 0; cb < 8; ++cb) {
            int c = cb*16 + l15;
            #pragma unroll
            for (int i = 0; i < 4; ++i) {
                int rrow = rbase + rt*16 + (lane >> 4)*4 + i;
                T6[((size_t)layer*NTAB + mt*128 + rrow) * HD + c] = acc2[rt][cb][i] + b2c[cb];
            }
        }
    }
}

// pack table rows i,i+1 as {bf16,bf16} in one u32
__global__ void packtab_kernel(const float* __restrict__ T6, uint* __restrict__ P6) {
    int idx = blockIdx.x * blockDim.x + threadIdx.x;
    if (idx >= 6 * NTAB * HD) return;
    int r = (idx >> 7) & (NTAB - 1);
    float v0 = T6[idx];
    float v1 = (r + 1 < NTAB) ? T6[idx + HD] : v0;
    P6[idx] = ((uint)f2bf(v0)) | (((uint)f2bf(v1)) << 16);
}

// ================= 64-row-tile GEMV (layer-0 c1 only): hxb = bf16(h @ (Bhi+Blo)) ====
__global__ __launch_bounds__(256) void gemv64_kernel(
        const float* __restrict__ A, const ushort* __restrict__ BThi,
        const ushort* __restrict__ BTlo, ushort* __restrict__ bdst, int mtiles) {
    __shared__ ushort A_[64 * 128];
    __shared__ ushort B_[128 * 128];
    char* Ab = (char*)A_;
    char* Bb = (char*)B_;
    const int tid  = threadIdx.x;
    const int lane = tid & 63;
    const int wave = tid >> 6;
    const int l15  = lane & 15;
    const int kgrp = (lane >> 4) * 8;
    const int rbase = wave * 16;

    for (int mt = blockIdx.x; mt < mtiles; mt += gridDim.x) {
        __syncthreads();
        #pragma unroll
        for (int p = 0; p < 8; ++p) {
            int rr = p * 8 + (tid >> 5);
            int k4 = (tid & 31) * 4;
            f32x4 v = *reinterpret_cast<const f32x4*>(&A[(size_t)(mt*64 + rr)*HD + k4]);
            u16x4 b;
            b.x = f2bf(v.x); b.y = f2bf(v.y); b.z = f2bf(v.z); b.w = f2bf(v.w);
            *reinterpret_cast<u16x4*>(&Ab[rr*256 + ((2*k4) ^ ((rr & 7) << 4))]) = b;
        }

        f32x4 acc[8];
        #pragma unroll
        for (int j = 0; j < 8; ++j) { acc[j].x=0.f; acc[j].y=0.f; acc[j].z=0.f; acc[j].w=0.f; }

        #pragma unroll
        for (int part = 0; part < 2; ++part) {
            const ushort* BT = part ? BTlo : BThi;
            __syncthreads();
            #pragma unroll
            for (int p = 0; p < 8; ++p) {
                int rr = p * 16 + (tid >> 4);
                int k8 = (tid & 15) * 8;
                u16x8 v = *reinterpret_cast<const u16x8*>(&BT[(size_t)rr*128 + k8]);
                *reinterpret_cast<u16x8*>(&Bb[rr*256 + ((2*k8) ^ ((rr & 7) << 4))]) = v;
            }
            __syncthreads();
            #pragma unroll
            for (int ks = 0; ks < 4; ++ks) {
                int k = ks*32 + kgrp;
                int r = rbase + l15;
                bf16x8 af = *reinterpret_cast<const bf16x8*>(&Ab[r*256 + ((2*k) ^ ((r & 7) << 4))]);
                #pragma unroll
                for (int cb = 0; cb < 8; ++cb) {
                    int c = cb*16 + l15;
                    bf16x8 bv = *reinterpret_cast<const bf16x8*>(&Bb[c*256 + ((2*k) ^ ((c & 7) << 4))]);
                    acc[cb] = __builtin_amdgcn_mfma_f32_16x16x32_bf16(af, bv, acc[cb], 0, 0, 0);
                }
            }
        }

        #pragma unroll
        for (int cb = 0; cb < 8; ++cb) {
            int c = cb*16 + l15;
            #pragma unroll
            for (int i = 0; i < 4; ++i) {
                int row = mt*64 + rbase + (lane >> 4)*4 + i;
                bdst[(size_t)row * HD + c] = f2bf(acc[cb][i]);
            }
        }
    }
}

// ================= fused node block (64-row, 3 GEMMs) =================
// GEMM1: t = ssp(aggb @ (c2hi+c2lo) + c2b)
// GEMM2: hv = h + t @ (lwhi+lwlo) + lb  -> h (skip write if LAST), bf16(hv) -> A_ LDS
// GEMM3: !LAST: hxbn = bf16(hv @ (c1nhi+c1nlo)) ; LAST: h1 = relu(hv @ lin1 + l1b)
// LDS: A 16K + B 32K + U 16K = 64 KB -> 2 blocks/CU.
template<bool LAST>
__global__ __launch_bounds__(256) void nodefused_kernel(
        const ushort* __restrict__ aggb,
        const ushort* __restrict__ c2hi, const ushort* __restrict__ c2lo,
        const float* __restrict__ c2b,
        const ushort* __restrict__ lwhi, const ushort* __restrict__ lwlo,
        const float* __restrict__ lb,
        const ushort* __restrict__ c1nhi, const ushort* __restrict__ c1nlo,
        const float* __restrict__ l1b,
        float* __restrict__ h, ushort* __restrict__ hxbn, float* __restrict__ h1,
        int mtiles) {
    __shared__ ushort A_[64 * 128];
    __shared__ ushort B_[128 * 128];
    __shared__ ushort U_[64 * 128];
    char* Ab = (char*)A_;
    char* Bb = (char*)B_;
    char* Ub = (char*)U_;
    const int tid  = threadIdx.x;
    const int lane = tid & 63;
    const int wave = tid >> 6;
    const int l15  = lane & 15;
    const int kgrp = (lane >> 4) * 8;
    const int rbase = wave * 16;

    float b1c[8], b2c[8], b3c[8];
    #pragma unroll
    for (int cb = 0; cb < 8; ++cb) {
        b1c[cb] = c2b[cb*16 + l15];
        b2c[cb] = lb[cb*16 + l15];
        b3c[cb] = LAST ? l1b[cb*16 + l15] : 0.0f;
    }

    for (int mt = blockIdx.x; mt < mtiles; mt += gridDim.x) {
        __syncthreads();   // prior iter's A_/B_/U_ reads done
        // stage A = aggb tile (bf16, swizzled)
        #pragma unroll
        for (int p = 0; p < 4; ++p) {
            int rr = p * 16 + (tid >> 4);
            int k8 = (tid & 15) * 8;
            u16x8 v = *reinterpret_cast<const u16x8*>(&aggb[(size_t)(mt*64 + rr)*HD + k8]);
            *reinterpret_cast<u16x8*>(&Ab[rr*256 + ((2*k8) ^ ((rr & 7) << 4))]) = v;
        }

        f32x4 acc[8];
        // ---- GEMM1: acc = A @ (c2hi+c2lo) ----
        #pragma unroll
        for (int j = 0; j < 8; ++j) { acc[j].x=0.f; acc[j].y=0.f; acc[j].z=0.f; acc[j].w=0.f; }
        #pragma unroll
        for (int part = 0; part < 2; ++part) {
            const ushort* BT = part ? c2lo : c2hi;
            __syncthreads();
            #pragma unroll
            for (int p = 0; p < 8; ++p) {
                int rr = p * 16 + (tid >> 4);
                int k8 = (tid & 15) * 8;
                u16x8 v = *reinterpret_cast<const u16x8*>(&BT[(size_t)rr*128 + k8]);
                *reinterpret_cast<u16x8*>(&Bb[rr*256 + ((2*k8) ^ ((rr & 7) << 4))]) = v;
            }
            __syncthreads();
            #pragma unroll
            for (int ks = 0; ks < 4; ++ks) {
                int k = ks*32 + kgrp;
                int r = rbase + l15;
                bf16x8 af = *reinterpret_cast<const bf16x8*>(&Ab[r*256 + ((2*k) ^ ((r & 7) << 4))]);
                #pragma unroll
                for (int cb = 0; cb < 8; ++cb) {
                    int c = cb*16 + l15;
                    bf16x8 bv = *reinterpret_cast<const bf16x8*>(&Bb[c*256 + ((2*k) ^ ((c & 7) << 4))]);
                    acc[cb] = __builtin_amdgcn_mfma_f32_16x16x32_bf16(af, bv, acc[cb], 0, 0, 0);
                }
            }
        }
        // epilogue1: ssp -> U_
        #pragma unroll
        for (int cb = 0; cb < 8; ++cb) {
            int c = cb*16 + l15;
            #pragma unroll
            for (int i = 0; i < 4; ++i) {
                int rrow = rbase + (lane >> 4)*4 + i;
                ushort us = f2bf(ssp_f(acc[cb][i] + b1c[cb]));
                *reinterpret_cast<ushort*>(&Ub[rrow*256 + ((2*c) ^ ((rrow & 7) << 4))]) = us;
            }
        }

        // ---- GEMM2: acc = U @ (lwhi+lwlo) ----
        #pragma unroll
        for (int j = 0; j < 8; ++j) { acc[j].x=0.f; acc[j].y=0.f; acc[j].z=0.f; acc[j].w=0.f; }
        #pragma unroll
        for (int part = 0; part < 2; ++part) {
            const ushort* BT = part ? lwlo : lwhi;
            __syncthreads();     // U_ visible + prior B reads done (+ GEMM1 A reads done)
            #pragma unroll
            for (int p = 0; p < 8; ++p) {
                int rr = p * 16 + (tid >> 4);
                int k8 = (tid & 15) * 8;
                u16x8 v = *reinterpret_cast<const u16x8*>(&BT[(size_t)rr*128 + k8]);
                *reinterpret_cast<u16x8*>(&Bb[rr*256 + ((2*k8) ^ ((rr & 7) << 4))]) = v;
            }
            __syncthreads();
            #pragma unroll
            for (int ks = 0; ks < 4; ++ks) {
                int k = ks*32 + kgrp;
                int r = rbase + l15;
                bf16x8 af = *reinterpret_cast<const bf16x8*>(&Ub[r*256 + ((2*k) ^ ((r & 7) << 4))]);
                #pragma unroll
                for (int cb = 0; cb < 8; ++cb) {
                    int c = cb*16 + l15;
                    bf16x8 bv = *reinterpret_cast<const bf16x8*>(&Bb[c*256 + ((2*k) ^ ((c & 7) << 4))]);
                    acc[cb] = __builtin_amdgcn_mfma_f32_16x16x32_bf16(af, bv, acc[cb], 0, 0, 0);
                }
            }
        }
        // epilogue2: hv = h + acc + lb -> h (if !LAST), bf16(hv) -> A_ (aggb reads long done)
        #pragma unroll
        for (int cb = 0; cb < 8; ++cb) {
            int c = cb*16 + l15;
            #pragma unroll
            for (int i = 0; i < 4; ++i) {
                int rrow = rbase + (lane >> 4)*4 + i;
                int row = mt*64 + rrow;
                size_t off = (size_t)row * HD + c;
                float hv = h[off] + acc[cb][i] + b2c[cb];
                if (!LAST) h[off] = hv;
                *reinterpret_cast<ushort*>(&Ab[rrow*256 + ((2*c) ^ ((rrow & 7) << 4))]) = f2bf(hv);
            }
        }

        // ---- GEMM3: acc = A_(new h) @ (c1nhi+c1nlo) ----
        #pragma unroll
        for (int j = 0; j < 8; ++j) { acc[j].x=0.f; acc[j].y=0.f; acc[j].z=0.f; acc[j].w=0.f; }
        #pragma unroll
        for (int part = 0; part < 2; ++part) {
            const ushort* BT = part ? c1nlo : c1nhi;
            __syncthreads();     // new A_ visible + prior B reads done
            #pragma unroll
            for (int p = 0; p < 8; ++p) {
                int rr = p * 16 + (tid >> 4);
                int k8 = (tid & 15) * 8;
                u16x8 v = *reinterpret_cast<const u16x8*>(&BT[(size_t)rr*128 + k8]);
                *reinterpret_cast<u16x8*>(&Bb[rr*256 + ((2*k8) ^ ((rr & 7) << 4))]) = v;
            }
            __syncthreads();
            #pragma unroll
            for (int ks = 0; ks < 4; ++ks) {
                int k = ks*32 + kgrp;
                int r = rbase + l15;
                bf16x8 af = *reinterpret_cast<const bf16x8*>(&Ab[r*256 + ((2*k) ^ ((r & 7) << 4))]);
                #pragma unroll
                for (int cb = 0; cb < 8; ++cb) {
                    int c = cb*16 + l15;
                    bf16x8 bv = *reinterpret_cast<const bf16x8*>(&Bb[c*256 + ((2*k) ^ ((c & 7) << 4))]);
                    acc[cb] = __builtin_amdgcn_mfma_f32_16x16x32_bf16(af, bv, acc[cb], 0, 0, 0);
                }
            }
        }
        // epilogue3
        #pragma unroll
        for (int cb = 0; cb < 8; ++cb) {
            int c = cb*16 + l15;
            #pragma unroll
            for (int i = 0; i < 4; ++i) {
                int row = mt*64 + rbase + (lane >> 4)*4 + i;
                size_t off = (size_t)row * HD + c;
                if (LAST) h1[off] = fmaxf(acc[cb][i] + b3c[cb], 0.0f);
                else      hxbn[off] = f2bf(acc[cb][i]);
            }
        }
    }
}

// ================= fused gather-lerp-segment-sum (4-slot unrolled) ============
__global__ __launch_bounds__(256) void gathersum_kernel(
        const uint* __restrict__ Tp, const uint2* __restrict__ meta,
        const int* __restrict__ rowp, const ushort* __restrict__ hxb,
        ushort* __restrict__ aggb, int N) {
    const int lane = threadIdx.x & 63;
    const int n = blockIdx.x * 4 + (threadIdx.x >> 6);
    if (n >= N) return;
    const int c0 = lane * 2;
    const int s0 = rowp[n], s1 = rowp[n + 1];
    float a0=0.f, a1=0.f, a2=0.f, a3=0.f, a4=0.f, a5=0.f, a6=0.f, a7=0.f;
    int s = s0;
    for (; s + 4 <= s1; s += 4) {
        uint2 m0 = meta[s], m1 = meta[s+1], m2 = meta[s+2], m3 = meta[s+3];
        uint2 t0 = *reinterpret_cast<const uint2*>(&Tp[(size_t)(m0.x >> 16) * HD + c0]);
        uint2 t1 = *reinterpret_cast<const uint2*>(&Tp[(size_t)(m1.x >> 16) * HD + c0]);
        uint2 t2 = *reinterpret_cast<const uint2*>(&Tp[(size_t)(m2.x >> 16) * HD + c0]);
        uint2 t3 = *reinterpret_cast<const uint2*>(&Tp[(size_t)(m3.x >> 16) * HD + c0]);
        uint  h0 = *reinterpret_cast<const uint*>(&hxb[(size_t)(m0.x & 0xFFFFu) * HD + c0]);
        uint  h1 = *reinterpret_cast<const uint*>(&hxb[(size_t)(m1.x & 0xFFFFu) * HD + c0]);
        uint  h2 = *reinterpret_cast<const uint*>(&hxb[(size_t)(m2.x & 0xFFFFu) * HD + c0]);
        uint  h3 = *reinterpret_cast<const uint*>(&hxb[(size_t)(m3.x & 0xFFFFu) * HD + c0]);
        float wa, wb, glo, ghi;
        wa = bf2f((ushort)(m0.y & 0xFFFFu)); wb = bf2f((ushort)(m0.y >> 16));
        glo = wa*__uint_as_float(t0.x << 16) + wb*__uint_as_float(t0.x & 0xFFFF0000u);
        ghi = wa*__uint_as_float(t0.y << 16) + wb*__uint_as_float(t0.y & 0xFFFF0000u);
        a0 += glo * __uint_as_float(h0 << 16);
        a1 += ghi * __uint_as_float(h0 & 0xFFFF0000u);
        wa = bf2f((ushort)(m1.y & 0xFFFFu)); wb = bf2f((ushort)(m1.y >> 16));
        glo = wa*__uint_as_float(t1.x << 16) + wb*__uint_as_float(t1.x & 0xFFFF0000u);
        ghi = wa*__uint_as_float(t1.y << 16) + wb*__uint_as_float(t1.y & 0xFFFF0000u);
        a2 += glo * __uint_as_float(h1 << 16);
        a3 += ghi * __uint_as_float(h1 & 0xFFFF0000u);
        wa = bf2f((ushort)(m2.y & 0xFFFFu)); wb = bf2f((ushort)(m2.y >> 16));
        glo = wa*__uint_as_float(t2.x << 16) + wb*__uint_as_float(t2.x & 0xFFFF0000u);
        ghi = wa*__uint_as_float(t2.y << 16) + wb*__uint_as_float(t2.y & 0xFFFF0000u);
        a4 += glo * __uint_as_float(h2 << 16);
        a5 += ghi * __uint_as_float(h2 & 0xFFFF0000u);
        wa = bf2f((ushort)(m3.y & 0xFFFFu)); wb = bf2f((ushort)(m3.y >> 16));
        glo = wa*__uint_as_float(t3.x << 16) + wb*__uint_as_float(t3.x & 0xFFFF0000u);
        ghi = wa*__uint_as_float(t3.y << 16) + wb*__uint_as_float(t3.y & 0xFFFF0000u);
        a6 += glo * __uint_as_float(h3 << 16);
        a7 += ghi * __uint_as_float(h3 & 0xFFFF0000u);
    }
    for (; s < s1; ++s) {
        uint2 m0 = meta[s];
        uint2 t0 = *reinterpret_cast<const uint2*>(&Tp[(size_t)(m0.x >> 16) * HD + c0]);
        uint  h0 = *reinterpret_cast<const uint*>(&hxb[(size_t)(m0.x & 0xFFFFu) * HD + c0]);
        float wa = bf2f((ushort)(m0.y & 0xFFFFu)), wb = bf2f((ushort)(m0.y >> 16));
        float glo = wa*__uint_as_float(t0.x << 16) + wb*__uint_as_float(t0.x & 0xFFFF0000u);
        float ghi = wa*__uint_as_float(t0.y << 16) + wb*__uint_as_float(t0.y & 0xFFFF0000u);
        a0 += glo * __uint_as_float(h0 << 16);
        a1 += ghi * __uint_as_float(h0 & 0xFFFF0000u);
    }
    uint out = ((uint)f2bf(a0 + a2 + a4 + a6)) | (((uint)f2bf(a1 + a3 + a5 + a7)) << 16);
    *reinterpret_cast<uint*>(&aggb[(size_t)n * HD + c0]) = out;
}

// ================= mean pool =================
__global__ void pool_kernel(const float* __restrict__ h1, const int* __restrict__ batch,
                            float* __restrict__ gsum, float* __restrict__ gcnt, int N) {
    __shared__ float pool[NGRAPH][HD];
    __shared__ float cnt[NGRAPH];
    const int t = threadIdx.x;
    #pragma unroll
    for (int g = 0; g < NGRAPH; ++g) pool[g][t] = 0.0f;
    if (t < NGRAPH) cnt[t] = 0.0f;
    __syncthreads();
    int chunk = (N + gridDim.x - 1) / gridDim.x;
    int n0 = blockIdx.x * chunk, n1 = min(N, n0 + chunk);
    for (int n = n0; n < n1; ++n) {
        int b = batch[n];
        pool[b][t] += h1[(size_t)n * HD + t];
        if (t == 0) cnt[b] += 1.0f;
    }
    __syncthreads();
    #pragma unroll
    for (int g = 0; g < NGRAPH; ++g) atomicAdd(&gsum[g*HD + t], pool[g][t]);
    if (t < NGRAPH) atomicAdd(&gcnt[t], cnt[t]);
}

// ================= head =================
__global__ void finalize_kernel(const float* __restrict__ gsum, const float* __restrict__ gcnt,
                                const float* __restrict__ l1w, const float* __restrict__ l1b,
                                const float* __restrict__ l2w, const float* __restrict__ l2b,
                                float* __restrict__ d_out) {
    __shared__ float ge[HD];
    __shared__ float h2[HD];
    const int g = blockIdx.x, t = threadIdx.x;
    float cnt = fmaxf(gcnt[g], 1.0f);
    float v = gsum[g*HD + t] / cnt;
    d_out[g*HD + t] = v;
    ge[t] = v;
    __syncthreads();
    float acc = l1b[t];
    #pragma unroll 8
    for (int k = 0; k < HD; ++k) acc += ge[k] * l1w[k*HD + t];
    h2[t] = fmaxf(acc, 0.0f);
    __syncthreads();
    if (t < NCLS) {
        float o = l2b[t];
        #pragma unroll 8
        for (int k = 0; k < HD; ++k) o += h2[k] * l2w[k*NCLS + t];
        d_out[NGRAPH*HD + g*NCLS + t] = o;
    }
}

extern "C" void kernel_launch(void* const* d_in, const int* in_sizes, int n_in,
                              void* d_out, int out_size, void* d_ws, size_t ws_size,
                              hipStream_t stream) {
    const float* x     = (const float*)d_in[0];
    const float* pos   = (const float*)d_in[1];
    const int*   eidx  = (const int*)d_in[2];
    const int*   batch = (const int*)d_in[3];
    const float* emb_w = (const float*)d_in[4];
    const float* emb_b = (const float*)d_in[5];
    const float* m1w   = (const float*)d_in[6];
    const float* m1b   = (const float*)d_in[7];
    const float* m2w   = (const float*)d_in[8];
    const float* m2b   = (const float*)d_in[9];
    const float* c1w   = (const float*)d_in[10];
    const float* c2w   = (const float*)d_in[11];
    const float* c2b   = (const float*)d_in[12];
    const float* lw    = (const float*)d_in[13];
    const float* lb    = (const float*)d_in[14];
    const float* l1w   = (const float*)d_in[15];
    const float* l1b   = (const float*)d_in[16];
    const float* l2w   = (const float*)d_in[17];
    const float* l2b   = (const float*)d_in[18];

    const int N = in_sizes[0] / 21;          // 20000
    const int E = in_sizes[2] / 2;           // 640000
    const int* row = eidx;
    const int* col = eidx + E;
    const int NT64 = (N + 63) / 64;          // 313
    const int NB   = (N + 255) / 256;        // 79
    const int Npad = NT64 * 64 + 64;

    size_t off = 0;
    char* base = (char*)d_ws;
    auto alloc = [&](size_t bytes) -> void* {
        off = (off + 255) & ~(size_t)255;
        void* p = base + off;
        off += bytes;
        return p;
    };
    int*    deg     = (int*)alloc((size_t)N * 4);
    int*    cursor  = (int*)alloc((size_t)N * 4);
    int*    rowp    = (int*)alloc((size_t)(N + 1) * 4);
    int*    bsum    = (int*)alloc(512 * 4);
    int*    boff    = (int*)alloc(512 * 4);
    uint2*  meta    = (uint2*)alloc((size_t)E * 8);
    float*  h       = (float*)alloc((size_t)Npad * HD * 4);
    ushort* hxb     = (ushort*)alloc((size_t)Npad * HD * 2);
    ushort* aggb    = (ushort*)alloc((size_t)Npad * HD * 2);
    float*  h1      = (float*)alloc((size_t)Npad * HD * 4);
    float*  T6      = (float*)alloc((size_t)6 * NTAB * HD * 4);
    uint*   P6      = (uint*)alloc((size_t)6 * NTAB * HD * 4);
    ushort* m1T     = (ushort*)alloc((size_t)6 * 128 * 64 * 2);
    ushort* nodeThi = (ushort*)alloc((size_t)19 * 128 * 128 * 2);
    ushort* nodeTlo = (ushort*)alloc((size_t)19 * 128 * 128 * 2);
    ushort* m2T     = (ushort*)alloc((size_t)6 * 128 * 128 * 2);
    float*  gsum    = (float*)alloc((size_t)NGRAPH * HD * 4);
    float*  gcnt    = (float*)alloc((size_t)NGRAPH * 4);

    // ---- one-time: weight prep + CSR + filter tables ----
    prep_kernel<<<1792, 256, 0, stream>>>(m1w, c1w, c2w, lw, l1w, m2w,
                                          m1T, nodeThi, nodeTlo, m2T);
    hipMemsetAsync(deg, 0, (size_t)N * 4, stream);
    hist_kernel<<<(E + 255)/256, 256, 0, stream>>>(col, deg, E);
    scan1_kernel<<<NB, 256, 0, stream>>>(deg, rowp, bsum, N);
    scan2_kernel<<<1, 256, 0, stream>>>(bsum, boff, NB, rowp + N);
    scan3_kernel<<<NB, 256, 0, stream>>>(rowp, boff, cursor, N);
    fill_kernel<<<(E + 255)/256, 256, 0, stream>>>(row, col, pos, cursor, meta, E);
    buildtab_kernel<<<6 * (NTAB/128), 256, 0, stream>>>(m1T, m2T, m1b, m2b, T6);
    packtab_kernel<<<(6*NTAB*HD + 255)/256, 256, 0, stream>>>(T6, P6);
    embed_kernel<<<(N*HD + 255)/256, 256, 0, stream>>>(x, emb_w, emb_b, h, N);

    // hxb for layer 0
    gemv64_kernel<<<NT64, 256, 0, stream>>>(h, nodeThi, nodeTlo, hxb, NT64);

    for (int l = 0; l < NLAYER; ++l) {
        const ushort* c2Thi = nodeThi + (size_t)(6 + l) * 16384;
        const ushort* c2Tlo = nodeTlo + (size_t)(6 + l) * 16384;
        const ushort* lThi  = nodeThi + (size_t)(12 + l) * 16384;
        const ushort* lTlo  = nodeTlo + (size_t)(12 + l) * 16384;

        gathersum_kernel<<<(N + 3)/4, 256, 0, stream>>>(
            P6 + (size_t)l * NTAB * HD, meta, rowp, hxb, aggb, N);

        if (l < NLAYER - 1) {
            const ushort* c1nhi = nodeThi + (size_t)(l + 1) * 16384;
            const ushort* c1nlo = nodeTlo + (size_t)(l + 1) * 16384;
            nodefused_kernel<false><<<NT64, 256, 0, stream>>>(
                aggb, c2Thi, c2Tlo, c2b + l*HD, lThi, lTlo, lb + l*HD,
                c1nhi, c1nlo, nullptr, h, hxb, nullptr, NT64);
        } else {
            const ushort* lin1hi = nodeThi + (size_t)18 * 16384;
            const ushort* lin1lo = nodeTlo + (size_t)18 * 16384;
            nodefused_kernel<true><<<NT64, 256, 0, stream>>>(
                aggb, c2Thi, c2Tlo, c2b + l*HD, lThi, lTlo, lb + l*HD,
                lin1hi, lin1lo, l1b, h, nullptr, h1, NT64);
        }
    }

    hipMemsetAsync(gsum, 0, (size_t)(NGRAPH*HD + NGRAPH) * 4, stream);
    pool_kernel<<<256, HD, 0, stream>>>(h1, batch, gsum, gcnt, N);
    finalize_kernel<<<NGRAPH, HD, 0, stream>>>(gsum, gcnt, l1w, l1b, l2w, l2b,
                                               (float*)d_out);
}